// Round 2
// baseline (1377.137 us; speedup 1.0000x reference)
//
#include <hip/hip_runtime.h>

typedef float f32x4 __attribute__((ext_vector_type(4)));
typedef _Float16 half_t;
typedef _Float16 h8 __attribute__((ext_vector_type(8)));
typedef _Float16 h4 __attribute__((ext_vector_type(4)));

__device__ __forceinline__ f32x4 mfma16(h8 a, h8 b, f32x4 c) {
  return __builtin_amdgcn_mfma_f32_16x16x32_f16(a, b, c, 0, 0, 0);
}

// ---------------- LayerNorm (f32 in -> f16 out) ----------------
__global__ __launch_bounds__(256) void ln_fwd(const float* __restrict__ x,
                                              const float* __restrict__ g,
                                              const float* __restrict__ b,
                                              half_t* __restrict__ out) {
  const int row = blockIdx.x;
  const int tid = threadIdx.x;
  const float4 v = ((const float4*)(x + (size_t)row * 1024))[tid];
  float s = v.x + v.y + v.z + v.w;
  float q = v.x * v.x + v.y * v.y + v.z * v.z + v.w * v.w;
#pragma unroll
  for (int m = 1; m < 64; m <<= 1) { s += __shfl_xor(s, m); q += __shfl_xor(q, m); }
  __shared__ float red[8];
  const int wave = tid >> 6, lane = tid & 63;
  if (lane == 0) { red[wave] = s; red[wave + 4] = q; }
  __syncthreads();
  s = red[0] + red[1] + red[2] + red[3];
  q = red[4] + red[5] + red[6] + red[7];
  const float mean = s * (1.0f / 1024.0f);
  const float var = q * (1.0f / 1024.0f) - mean * mean;
  const float rstd = rsqrtf(var + 1e-5f);
  const float4 gv = ((const float4*)g)[tid];
  const float4 bv = ((const float4*)b)[tid];
  h4 o;
  o[0] = (half_t)((v.x - mean) * rstd * gv.x + bv.x);
  o[1] = (half_t)((v.y - mean) * rstd * gv.y + bv.y);
  o[2] = (half_t)((v.z - mean) * rstd * gv.z + bv.z);
  o[3] = (half_t)((v.w - mean) * rstd * gv.w + bv.w);
  *(h4*)(out + (size_t)row * 1024 + tid * 4) = o;
}

// ---------------- f32 -> f16 convert ----------------
__global__ __launch_bounds__(256) void cvt_f2h(const float* __restrict__ in,
                                               half_t* __restrict__ out, int n) {
  const int i = (blockIdx.x * 256 + threadIdx.x) * 4;
  if (i < n) {
    const float4 v = *(const float4*)(in + i);
    h4 o = {(half_t)v.x, (half_t)v.y, (half_t)v.z, (half_t)v.w};
    *(h4*)(out + i) = o;
  }
}

// ---------------- w1 [E,D,H] -> w1t [(E*H), D]  (f16) ----------------
__global__ __launch_bounds__(256) void tr_w1(const float* __restrict__ w1,
                                             half_t* __restrict__ w1t) {
  __shared__ float tile[32][33];
  const int e = blockIdx.z;
  const int tx = threadIdx.x & 31, ty = threadIdx.x >> 5;
  const int hh = blockIdx.x * 32 + tx;
#pragma unroll
  for (int i = 0; i < 4; ++i) {
    const int d = blockIdx.y * 32 + ty + i * 8;
    tile[ty + i * 8][tx] = w1[(size_t)e * 262144 + (size_t)d * 256 + hh];
  }
  __syncthreads();
#pragma unroll
  for (int i = 0; i < 4; ++i) {
    const int hho = blockIdx.x * 32 + ty + i * 8;
    const int k = blockIdx.y * 32 + tx;
    w1t[(size_t)(e * 256 + hho) * 1024 + k] = (half_t)tile[tx][ty + i * 8];
  }
}

// ---------------- w2 [E,H,D] -> w2t [D, (E*H)]  (f16) ----------------
__global__ __launch_bounds__(256) void tr_w2(const float* __restrict__ w2,
                                             half_t* __restrict__ w2t) {
  __shared__ float tile[32][33];
  const int e = blockIdx.z;
  const int tx = threadIdx.x & 31, ty = threadIdx.x >> 5;
  const int d_in = blockIdx.x * 32 + tx;
#pragma unroll
  for (int i = 0; i < 4; ++i) {
    const int hh = blockIdx.y * 32 + ty + i * 8;
    tile[ty + i * 8][tx] = w2[(size_t)e * 262144 + (size_t)hh * 1024 + d_in];
  }
  __syncthreads();
#pragma unroll
  for (int i = 0; i < 4; ++i) {
    const int d = blockIdx.x * 32 + ty + i * 8;
    const int hh = blockIdx.y * 32 + tx;
    w2t[(size_t)d * 4096 + e * 256 + hh] = (half_t)tile[tx][ty + i * 8];
  }
}

// ---------------- 128x128 MFMA GEMM, A[M,K] x Bt[N,K]^T ----------------
// EPI 0: Ch = f16(acc + bias)                       (QKV)
// EPI 1: Cf = res + acc + bias                      (out-proj + residual)
// EPI 2: Ch = f16(gelu(acc + bias) * gd[row, col>>8]) (MoE up)
// EPI 3: Cf = res + acc                             (MoE down accumulate)
template <int EPI>
__global__ __launch_bounds__(256) void gemm128(const half_t* __restrict__ A,
                                               const half_t* __restrict__ Bt,
                                               int N, int K,
                                               const float* __restrict__ bias,
                                               const float* __restrict__ res,
                                               const float* __restrict__ gd,
                                               half_t* __restrict__ Ch,
                                               float* __restrict__ Cf) {
  __shared__ half_t As[128 * 64];
  __shared__ half_t Bs[128 * 64];
  const int tid = threadIdx.x;
  const int wave = tid >> 6, lane = tid & 63;
  const int l15 = lane & 15, g = lane >> 4;
  const int wr = wave >> 1, wc = wave & 1;
  const int by = blockIdx.y, bx = blockIdx.x;
  f32x4 acc[4][4] = {};
  for (int k0 = 0; k0 < K; k0 += 64) {
#pragma unroll
    for (int j = 0; j < 4; ++j) {
      const int C0 = (j * 4 + wave) * 64;
      const int c = C0 + lane;
      const int row = c >> 3, col0 = (c & 7) << 3;
      __builtin_amdgcn_global_load_lds(
          (const __attribute__((address_space(1))) void*)(A + (size_t)(by * 128 + row) * K + k0 + col0),
          (__attribute__((address_space(3))) void*)(As + C0 * 8), 16, 0, 0);
    }
#pragma unroll
    for (int j = 0; j < 4; ++j) {
      const int C0 = (j * 4 + wave) * 64;
      const int c = C0 + lane;
      const int row = c >> 3, col0 = (c & 7) << 3;
      __builtin_amdgcn_global_load_lds(
          (const __attribute__((address_space(1))) void*)(Bt + (size_t)(bx * 128 + row) * K + k0 + col0),
          (__attribute__((address_space(3))) void*)(Bs + C0 * 8), 16, 0, 0);
    }
    __syncthreads();
#pragma unroll
    for (int kk = 0; kk < 2; ++kk) {
      h8 a[4], b[4];
#pragma unroll
      for (int m = 0; m < 4; ++m)
        a[m] = *(const h8*)(As + (wr * 64 + m * 16 + l15) * 64 + kk * 32 + g * 8);
#pragma unroll
      for (int n = 0; n < 4; ++n)
        b[n] = *(const h8*)(Bs + (wc * 64 + n * 16 + l15) * 64 + kk * 32 + g * 8);
#pragma unroll
      for (int m = 0; m < 4; ++m)
#pragma unroll
        for (int n = 0; n < 4; ++n)
          acc[m][n] = mfma16(a[m], b[n], acc[m][n]);
    }
    __syncthreads();
  }
#pragma unroll
  for (int m = 0; m < 4; ++m) {
#pragma unroll
    for (int n = 0; n < 4; ++n) {
      const int col = bx * 128 + wc * 64 + n * 16 + l15;
      float bv = 0.0f;
      if constexpr (EPI != 3) bv = bias[col];
#pragma unroll
      for (int r = 0; r < 4; ++r) {
        const int row = by * 128 + wr * 64 + m * 16 + g * 4 + r;
        const float v = acc[m][n][r] + bv;
        if constexpr (EPI == 0) {
          Ch[(size_t)row * N + col] = (half_t)v;
        } else if constexpr (EPI == 1) {
          Cf[(size_t)row * N + col] = res[(size_t)row * N + col] + v;
        } else if constexpr (EPI == 2) {
          const float gel = 0.5f * v * (1.0f + erff(v * 0.70710678118f));
          Ch[(size_t)row * N + col] = (half_t)(gel * gd[row * 16 + (col >> 8)]);
        } else {
          Cf[(size_t)row * N + col] = res[(size_t)row * N + col] + v;
        }
      }
    }
  }
}

// ---------------- fused flash attention ----------------
// grid (8 qtiles, 512 = b*16+h); block 256 (4 waves x 16 q-rows)
__global__ __launch_bounds__(256) void attn_fwd(const half_t* __restrict__ qkv,
                                                half_t* __restrict__ ctx) {
  const int bh = blockIdx.y;
  const int b = bh >> 4, h = bh & 15;
  const int qbase = blockIdx.x * 64;
  const int tid = threadIdx.x;
  const int wave = tid >> 6, lane = tid & 63;
  const int l15 = lane & 15, g = lane >> 4;
  __shared__ half_t K_s[2][32 * 64];
  __shared__ half_t Vt_s[2][64 * 32];
  __shared__ half_t P_s[4][16 * 32];

  const size_t qrow = (size_t)(b * 512 + qbase + wave * 16 + l15);
  h8 aq0 = *(const h8*)(qkv + qrow * 3072 + h * 64 + g * 8);
  h8 aq1 = *(const h8*)(qkv + qrow * 3072 + h * 64 + 32 + g * 8);
  aq0 = aq0 * (half_t)0.125f;  // fold 1/sqrt(dh) into Q
  aq1 = aq1 * (half_t)0.125f;

  float mr[4], sr[4];
  f32x4 o[4] = {};
#pragma unroll
  for (int r = 0; r < 4; ++r) { mr[r] = -1e30f; sr[r] = 0.0f; }

  const int key = tid >> 3, c0 = (tid & 7) << 3;
  const half_t* kbase = qkv + 1024 + h * 64 + c0;
  const half_t* vbase = qkv + 2048 + h * 64 + c0;

  for (int kt = 0; kt < 16; ++kt) {
    const int buf = kt & 1;
    const size_t krow = (size_t)(b * 512 + kt * 32 + key);
    const h8 kv = *(const h8*)(kbase + krow * 3072);
    *(h8*)(&K_s[buf][key * 64 + c0]) = kv;
    const h8 vv = *(const h8*)(vbase + krow * 3072);
#pragma unroll
    for (int j = 0; j < 8; ++j) Vt_s[buf][(c0 + j) * 32 + key] = vv[j];
    __syncthreads();

    f32x4 s0 = {0.f, 0.f, 0.f, 0.f}, s1 = {0.f, 0.f, 0.f, 0.f};
    s0 = mfma16(aq0, *(const h8*)(&K_s[buf][l15 * 64 + g * 8]), s0);
    s0 = mfma16(aq1, *(const h8*)(&K_s[buf][l15 * 64 + 32 + g * 8]), s0);
    s1 = mfma16(aq0, *(const h8*)(&K_s[buf][(16 + l15) * 64 + g * 8]), s1);
    s1 = mfma16(aq1, *(const h8*)(&K_s[buf][(16 + l15) * 64 + 32 + g * 8]), s1);

#pragma unroll
    for (int r = 0; r < 4; ++r) {
      const float a0 = s0[r], a1 = s1[r];
      float tm = fmaxf(a0, a1);
#pragma unroll
      for (int msk = 1; msk < 16; msk <<= 1) tm = fmaxf(tm, __shfl_xor(tm, msk));
      const float mnew = fmaxf(mr[r], tm);
      const float alpha = __expf(mr[r] - mnew);
      const float p0 = __expf(a0 - mnew), p1 = __expf(a1 - mnew);
      float rs = p0 + p1;
#pragma unroll
      for (int msk = 1; msk < 16; msk <<= 1) rs += __shfl_xor(rs, msk);
      sr[r] = sr[r] * alpha + rs;
      mr[r] = mnew;
#pragma unroll
      for (int d = 0; d < 4; ++d) o[d][r] *= alpha;
      P_s[wave][(g * 4 + r) * 32 + l15] = (half_t)p0;
      P_s[wave][(g * 4 + r) * 32 + 16 + l15] = (half_t)p1;
    }
    __syncthreads();

    const h8 pa = *(const h8*)(&P_s[wave][l15 * 32 + g * 8]);
#pragma unroll
    for (int d = 0; d < 4; ++d)
      o[d] = mfma16(pa, *(const h8*)(&Vt_s[buf][(d * 16 + l15) * 32 + g * 8]), o[d]);
  }
#pragma unroll
  for (int d = 0; d < 4; ++d) {
#pragma unroll
    for (int r = 0; r < 4; ++r) {
      const size_t row = (size_t)(b * 512 + qbase + wave * 16 + g * 4 + r);
      ctx[row * 1024 + h * 64 + d * 16 + l15] = (half_t)(o[d][r] / sr[r]);
    }
  }
}

// ---------------- gating: logits, softmax, probs, top-8, gate_dense, mean_p ----------------
__global__ __launch_bounds__(256) void gate_fwd(const half_t* __restrict__ h3,
                                                const float* __restrict__ gate_w,
                                                const int* __restrict__ task_id,
                                                float* __restrict__ probs,
                                                float* __restrict__ gd,
                                                float* __restrict__ mp) {
  const int tid = threadIdx.x, wave = tid >> 6, lane = tid & 63;
  const float* gw = gate_w + (size_t)task_id[0] * 16384;
  __shared__ float mp_part[16];
  if (tid < 16) mp_part[tid] = 0.0f;
  __syncthreads();
  float mpl[16];
#pragma unroll
  for (int e = 0; e < 16; ++e) mpl[e] = 0.0f;
  const int t0 = blockIdx.x * 64 + wave * 16;
  for (int tt = 0; tt < 16; ++tt) {
    const int t = t0 + tt;
    float acc[16];
#pragma unroll
    for (int e = 0; e < 16; ++e) acc[e] = 0.0f;
#pragma unroll
    for (int i = 0; i < 16; ++i) {
      const int d = i * 64 + lane;
      const float hv = (float)h3[(size_t)t * 1024 + d];
      const float4* gp = (const float4*)(gw + d * 16);
      const float4 g0 = gp[0], g1 = gp[1], g2 = gp[2], g3 = gp[3];
      acc[0] = fmaf(hv, g0.x, acc[0]);  acc[1] = fmaf(hv, g0.y, acc[1]);
      acc[2] = fmaf(hv, g0.z, acc[2]);  acc[3] = fmaf(hv, g0.w, acc[3]);
      acc[4] = fmaf(hv, g1.x, acc[4]);  acc[5] = fmaf(hv, g1.y, acc[5]);
      acc[6] = fmaf(hv, g1.z, acc[6]);  acc[7] = fmaf(hv, g1.w, acc[7]);
      acc[8] = fmaf(hv, g2.x, acc[8]);  acc[9] = fmaf(hv, g2.y, acc[9]);
      acc[10] = fmaf(hv, g2.z, acc[10]); acc[11] = fmaf(hv, g2.w, acc[11]);
      acc[12] = fmaf(hv, g3.x, acc[12]); acc[13] = fmaf(hv, g3.y, acc[13]);
      acc[14] = fmaf(hv, g3.z, acc[14]); acc[15] = fmaf(hv, g3.w, acc[15]);
    }
#pragma unroll
    for (int msk = 32; msk >= 1; msk >>= 1)
#pragma unroll
      for (int e = 0; e < 16; ++e) acc[e] += __shfl_xor(acc[e], msk);
    float mx = acc[0];
#pragma unroll
    for (int e = 1; e < 16; ++e) mx = fmaxf(mx, acc[e]);
    float p[16];
    float sum = 0.0f;
#pragma unroll
    for (int e = 0; e < 16; ++e) { p[e] = __expf(acc[e] - mx); sum += p[e]; }
    const float inv = 1.0f / sum;
#pragma unroll
    for (int e = 0; e < 16; ++e) p[e] *= inv;
    float myp = p[0];
#pragma unroll
    for (int e = 1; e < 16; ++e) myp = (lane == e) ? p[e] : myp;
    if (lane < 16) probs[(size_t)t * 16 + lane] = myp;
#pragma unroll
    for (int e = 0; e < 16; ++e) mpl[e] += p[e];
    // top-8 selection (ties -> lowest index, matching lax.top_k)
    float v[16];
#pragma unroll
    for (int e = 0; e < 16; ++e) v[e] = p[e];
    float topv[8];
    int topi[8];
#pragma unroll
    for (int k = 0; k < 8; ++k) {
      float vm = -1.0f;
      int im = 0;
#pragma unroll
      for (int e = 0; e < 16; ++e) {
        const bool gt = v[e] > vm;
        vm = gt ? v[e] : vm;
        im = gt ? e : im;
      }
      topv[k] = vm; topi[k] = im;
#pragma unroll
      for (int e = 0; e < 16; ++e) v[e] = (e == im) ? -1.0f : v[e];
    }
    float ts = 1e-6f;
#pragma unroll
    for (int k = 0; k < 8; ++k) ts += topv[k];
    const float tinv = 1.0f / ts;
    float gval = 0.0f;
#pragma unroll
    for (int k = 0; k < 8; ++k) gval = (topi[k] == lane) ? topv[k] * tinv : gval;
    if (lane < 16) gd[(size_t)t * 16 + lane] = gval;
  }
  if (lane == 0) {
#pragma unroll
    for (int e = 0; e < 16; ++e) atomicAdd(&mp_part[e], mpl[e]);
  }
  __syncthreads();
  if (tid < 16) atomicAdd(&mp[tid], mp_part[tid]);
}

// ---------------- aux loss ----------------
__global__ void aux_fwd(const float* __restrict__ mp, float* __restrict__ out) {
  if (threadIdx.x == 0) {
    float a = 0.0f;
    for (int e = 0; e < 16; ++e) {
      const float m = mp[e] * (1.0f / 16384.0f);
      a += m * logf(m + 1e-6f);
    }
    out[0] = 5e-4f * a;
  }
}

// ---------------- d_out += gate_dense @ b2 ----------------
__global__ __launch_bounds__(256) void bias2_add(const float* __restrict__ gd,
                                                 const float* __restrict__ b2,
                                                 float* __restrict__ out) {
  const int t = blockIdx.x, tid = threadIdx.x;
  __shared__ float gds[16];
  if (tid < 16) gds[tid] = gd[(size_t)t * 16 + tid];
  __syncthreads();
  float4 v = *(const float4*)(out + (size_t)t * 1024 + tid * 4);
#pragma unroll
  for (int e = 0; e < 16; ++e) {
    const float gv = gds[e];
    const float4 bv = *(const float4*)(b2 + e * 1024 + tid * 4);
    v.x = fmaf(gv, bv.x, v.x);
    v.y = fmaf(gv, bv.y, v.y);
    v.z = fmaf(gv, bv.z, v.z);
    v.w = fmaf(gv, bv.w, v.w);
  }
  *(float4*)(out + (size_t)t * 1024 + tid * 4) = v;
}

extern "C" void kernel_launch(void* const* d_in, const int* in_sizes, int n_in,
                              void* d_out, int out_size, void* d_ws, size_t ws_size,
                              hipStream_t stream) {
  const float* tgt = (const float*)d_in[0];
  const float* ln1_g = (const float*)d_in[2];
  const float* ln1_b = (const float*)d_in[3];
  const float* ln3_g = (const float*)d_in[4];
  const float* ln3_b = (const float*)d_in[5];
  const float* Wqkv = (const float*)d_in[6];
  const float* bqkv = (const float*)d_in[7];
  const float* Wout = (const float*)d_in[8];
  const float* bout = (const float*)d_in[9];
  const float* gate_w = (const float*)d_in[10];
  const float* w1 = (const float*)d_in[11];
  const float* b1 = (const float*)d_in[12];
  const float* w2 = (const float*)d_in[13];
  const float* b2 = (const float*)d_in[14];
  const int* task = (const int*)d_in[15];
  float* out = (float*)d_out;
  char* ws = (char*)d_ws;

  // ws layout (bytes):
  half_t* h = (half_t*)(ws + 0ull);                   // 32MB  [T,1024] (h, later h3)
  half_t* qkv = (half_t*)(ws + 33554432ull);          // 96MB  [T,3072]
  half_t* ctx = (half_t*)(ws + 134217728ull);         // 32MB  [T,1024]
  half_t* uw = (half_t*)(ws + 33554432ull);           // 128MB [T,4096] overlays qkv+ctx
  half_t* wqkv_h = (half_t*)(ws + 167772160ull);      // 6MB
  half_t* wout_h = (half_t*)(ws + 174063616ull);      // 2MB
  half_t* w1t = (half_t*)(ws + 176160768ull);         // 8MB
  half_t* w2t = (half_t*)(ws + 184549376ull);         // 8MB
  float* gd = (float*)(ws + 192937984ull);            // 1MB [T,16]
  float* mp = (float*)(ws + 193986560ull);            // 64B [16]

  hipMemsetAsync(mp, 0, 64, stream);
  cvt_f2h<<<3072, 256, 0, stream>>>(Wqkv, wqkv_h, 3145728);
  cvt_f2h<<<1024, 256, 0, stream>>>(Wout, wout_h, 1048576);
  tr_w1<<<dim3(8, 32, 16), 256, 0, stream>>>(w1, w1t);
  tr_w2<<<dim3(32, 8, 16), 256, 0, stream>>>(w2, w2t);

  ln_fwd<<<16384, 256, 0, stream>>>(tgt, ln1_g, ln1_b, h);
  gemm128<0><<<dim3(24, 128), 256, 0, stream>>>(h, wqkv_h, 3072, 1024, bqkv, nullptr, nullptr, qkv, nullptr);
  attn_fwd<<<dim3(8, 512), 256, 0, stream>>>(qkv, ctx);
  gemm128<1><<<dim3(8, 128), 256, 0, stream>>>(ctx, wout_h, 1024, 1024, bout, tgt, nullptr, nullptr, out);

  ln_fwd<<<16384, 256, 0, stream>>>(out, ln3_g, ln3_b, h);
  gate_fwd<<<256, 256, 0, stream>>>(h, gate_w, task, out + 16777217, gd, mp);
  aux_fwd<<<1, 64, 0, stream>>>(mp, out + 16777216);
  bias2_add<<<16384, 256, 0, stream>>>(gd, b2, out);
  gemm128<2><<<dim3(32, 128), 256, 0, stream>>>(h, w1t, 4096, 1024, b1, nullptr, gd, uw, nullptr);
  gemm128<3><<<dim3(8, 128), 256, 0, stream>>>(uw, w2t, 1024, 4096, nullptr, out, nullptr, nullptr, out);
}

// Round 3
// 1277.946 us; speedup vs baseline: 1.0776x; 1.0776x over previous
//
#include <hip/hip_runtime.h>

typedef float f32x4 __attribute__((ext_vector_type(4)));
typedef _Float16 half_t;
typedef _Float16 h8 __attribute__((ext_vector_type(8)));
typedef _Float16 h4 __attribute__((ext_vector_type(4)));

__device__ __forceinline__ f32x4 mfma16(h8 a, h8 b, f32x4 c) {
  return __builtin_amdgcn_mfma_f32_16x16x32_f16(a, b, c, 0, 0, 0);
}

// ---------------- LayerNorm (f32 in -> f16 out) ----------------
__global__ __launch_bounds__(256) void ln_fwd(const float* __restrict__ x,
                                              const float* __restrict__ g,
                                              const float* __restrict__ b,
                                              half_t* __restrict__ out) {
  const int row = blockIdx.x;
  const int tid = threadIdx.x;
  const float4 v = ((const float4*)(x + (size_t)row * 1024))[tid];
  float s = v.x + v.y + v.z + v.w;
  float q = v.x * v.x + v.y * v.y + v.z * v.z + v.w * v.w;
#pragma unroll
  for (int m = 1; m < 64; m <<= 1) { s += __shfl_xor(s, m); q += __shfl_xor(q, m); }
  __shared__ float red[8];
  const int wave = tid >> 6, lane = tid & 63;
  if (lane == 0) { red[wave] = s; red[wave + 4] = q; }
  __syncthreads();
  s = red[0] + red[1] + red[2] + red[3];
  q = red[4] + red[5] + red[6] + red[7];
  const float mean = s * (1.0f / 1024.0f);
  const float var = q * (1.0f / 1024.0f) - mean * mean;
  const float rstd = rsqrtf(var + 1e-5f);
  const float4 gv = ((const float4*)g)[tid];
  const float4 bv = ((const float4*)b)[tid];
  h4 o;
  o[0] = (half_t)((v.x - mean) * rstd * gv.x + bv.x);
  o[1] = (half_t)((v.y - mean) * rstd * gv.y + bv.y);
  o[2] = (half_t)((v.z - mean) * rstd * gv.z + bv.z);
  o[3] = (half_t)((v.w - mean) * rstd * gv.w + bv.w);
  *(h4*)(out + (size_t)row * 1024 + tid * 4) = o;
}

// ---------------- f32 -> f16 convert ----------------
__global__ __launch_bounds__(256) void cvt_f2h(const float* __restrict__ in,
                                               half_t* __restrict__ out, int n) {
  const int i = (blockIdx.x * 256 + threadIdx.x) * 4;
  if (i < n) {
    const float4 v = *(const float4*)(in + i);
    h4 o = {(half_t)v.x, (half_t)v.y, (half_t)v.z, (half_t)v.w};
    *(h4*)(out + i) = o;
  }
}

// ---------------- w1 [E,D,H] -> w1t [(E*H), D]  (f16) ----------------
__global__ __launch_bounds__(256) void tr_w1(const float* __restrict__ w1,
                                             half_t* __restrict__ w1t) {
  __shared__ float tile[32][33];
  const int e = blockIdx.z;
  const int tx = threadIdx.x & 31, ty = threadIdx.x >> 5;
  const int hh = blockIdx.x * 32 + tx;
#pragma unroll
  for (int i = 0; i < 4; ++i) {
    const int d = blockIdx.y * 32 + ty + i * 8;
    tile[ty + i * 8][tx] = w1[(size_t)e * 262144 + (size_t)d * 256 + hh];
  }
  __syncthreads();
#pragma unroll
  for (int i = 0; i < 4; ++i) {
    const int hho = blockIdx.x * 32 + ty + i * 8;
    const int k = blockIdx.y * 32 + tx;
    w1t[(size_t)(e * 256 + hho) * 1024 + k] = (half_t)tile[tx][ty + i * 8];
  }
}

// ---------------- w2 [E,H,D] -> w2t [D, (E*H)]  (f16) ----------------
__global__ __launch_bounds__(256) void tr_w2(const float* __restrict__ w2,
                                             half_t* __restrict__ w2t) {
  __shared__ float tile[32][33];
  const int e = blockIdx.z;
  const int tx = threadIdx.x & 31, ty = threadIdx.x >> 5;
  const int d_in = blockIdx.x * 32 + tx;
#pragma unroll
  for (int i = 0; i < 4; ++i) {
    const int hh = blockIdx.y * 32 + ty + i * 8;
    tile[ty + i * 8][tx] = w2[(size_t)e * 262144 + (size_t)hh * 1024 + d_in];
  }
  __syncthreads();
#pragma unroll
  for (int i = 0; i < 4; ++i) {
    const int d = blockIdx.x * 32 + ty + i * 8;
    const int hh = blockIdx.y * 32 + tx;
    w2t[(size_t)d * 4096 + e * 256 + hh] = (half_t)tile[tx][ty + i * 8];
  }
}

// ---------------- 256x256 phased MFMA GEMM, A[M,K] x Bt[N,K]^T ----------------
// 8 waves (2M x 4N), per-wave 128x64 out, BK=64, dbuf 2 K-tiles (128 KiB LDS).
// 4 phases per K-tile (one C-quadrant each), counted vmcnt(8), XOR-swizzled LDS.
// EPI 0: Ch = f16(acc + bias)                          (QKV)
// EPI 1: Cf = res + acc + bias                         (out-proj + residual)
// EPI 2: Ch = f16(gelu(acc + bias) * gd[row, col>>8])  (MoE up)
// EPI 3: Cf = res + acc                                (MoE down accumulate)
template <int EPI>
__global__ __launch_bounds__(512, 2) void gemm256(const half_t* __restrict__ A,
                                                  const half_t* __restrict__ Bt,
                                                  int N, int K, int nbx,
                                                  const float* __restrict__ bias,
                                                  const float* __restrict__ res,
                                                  const float* __restrict__ gd,
                                                  half_t* __restrict__ Ch,
                                                  float* __restrict__ Cf) {
  __shared__ half_t lds[2][2][256 * 64];  // [slot][A/B][row*64 + col]
  const int tid = threadIdx.x;
  const int wave = tid >> 6, lane = tid & 63;
  const int l15 = lane & 15, g = lane >> 4;
  const int wr = wave >> 2, wc = wave & 3;

  // XCD-aware bijective swizzle (all grids here are divisible by 8)
  const int nwg = gridDim.x;
  const int bid = blockIdx.x;
  const int swz = (bid & 7) * (nwg >> 3) + (bid >> 3);
  const int bx = swz % nbx, by = swz / nbx;

  const int NT = K >> 6;
  f32x4 acc[8][4] = {};

  // stage one K-tile (A 256x64 + B 256x64) into slot kt&1, linear LDS dest,
  // global source column pre-permuted by slot^(row&7) (16B granules).
  auto stageAB = [&](int kt) {
    const int bt = kt & 1;
    const size_t abase = (size_t)(by * 256) * K + kt * 64;
    const size_t bbase = (size_t)(bx * 256) * K + kt * 64;
#pragma unroll
    for (int j = 0; j < 4; ++j) {
      const int c = tid + j * 512;
      const int row = c >> 3, sl = c & 7;
      const int col = (sl ^ (row & 7)) << 3;
      __builtin_amdgcn_global_load_lds(
          (const __attribute__((address_space(1))) void*)(A + abase + (size_t)row * K + col),
          (__attribute__((address_space(3))) void*)(&lds[bt][0][c * 8]), 16, 0, 0);
      __builtin_amdgcn_global_load_lds(
          (const __attribute__((address_space(1))) void*)(Bt + bbase + (size_t)row * K + col),
          (__attribute__((address_space(3))) void*)(&lds[bt][1][c * 8]), 16, 0, 0);
    }
  };

  stageAB(0);
  for (int kt = 0; kt < NT; ++kt) {
    const int bt = kt & 1;
    if (kt + 1 < NT) {
      stageAB(kt + 1);
      asm volatile("s_waitcnt vmcnt(8)" ::: "memory");
    } else {
      asm volatile("s_waitcnt vmcnt(0)" ::: "memory");
    }
    __builtin_amdgcn_s_barrier();  // slot bt fully staged (all waves vmcnt'd)

    h8 a[4][2], b[2][2];

#define RD_A(QM)                                                            \
  _Pragma("unroll") for (int m4 = 0; m4 < 4; ++m4)                          \
  _Pragma("unroll") for (int kk = 0; kk < 2; ++kk) {                        \
    const int row = wr * 128 + (QM)*64 + m4 * 16 + l15;                     \
    const int sl = ((kk << 2) | g) ^ (row & 7);                             \
    a[m4][kk] = *(const h8*)(&lds[bt][0][row * 64 + sl * 8]);               \
  }
#define RD_B(QN)                                                            \
  _Pragma("unroll") for (int n2 = 0; n2 < 2; ++n2)                          \
  _Pragma("unroll") for (int kk = 0; kk < 2; ++kk) {                        \
    const int row = wc * 64 + (QN)*32 + n2 * 16 + l15;                      \
    const int sl = ((kk << 2) | g) ^ (row & 7);                             \
    b[n2][kk] = *(const h8*)(&lds[bt][1][row * 64 + sl * 8]);               \
  }
#define MMA(QM, QN)                                                         \
  __builtin_amdgcn_s_barrier();                                             \
  asm volatile("s_waitcnt lgkmcnt(0)" ::: "memory");                        \
  __builtin_amdgcn_sched_barrier(0);                                        \
  __builtin_amdgcn_s_setprio(1);                                            \
  _Pragma("unroll") for (int m4 = 0; m4 < 4; ++m4)                          \
  _Pragma("unroll") for (int n2 = 0; n2 < 2; ++n2)                          \
  _Pragma("unroll") for (int kk = 0; kk < 2; ++kk)                          \
    acc[(QM)*4 + m4][(QN)*2 + n2] =                                         \
        mfma16(a[m4][kk], b[n2][kk], acc[(QM)*4 + m4][(QN)*2 + n2]);        \
  __builtin_amdgcn_s_setprio(0);                                            \
  __builtin_amdgcn_s_barrier();

    // phase 0: quad (0,0)
    RD_A(0) RD_B(0) MMA(0, 0)
    // phase 1: quad (0,1)
    RD_B(1) MMA(0, 1)
    // phase 2: quad (1,1)
    RD_A(1) MMA(1, 1)
    // phase 3: quad (1,0)
    RD_B(0) MMA(1, 0)
#undef RD_A
#undef RD_B
#undef MMA
  }

  // epilogue
#pragma unroll
  for (int m = 0; m < 8; ++m) {
#pragma unroll
    for (int n = 0; n < 4; ++n) {
      const int col = bx * 256 + wc * 64 + n * 16 + l15;
      float bv = 0.0f;
      if constexpr (EPI != 3) bv = bias[col];
#pragma unroll
      for (int r = 0; r < 4; ++r) {
        const int row = by * 256 + wr * 128 + m * 16 + g * 4 + r;
        const float v = acc[m][n][r] + bv;
        if constexpr (EPI == 0) {
          Ch[(size_t)row * N + col] = (half_t)v;
        } else if constexpr (EPI == 1) {
          Cf[(size_t)row * N + col] = res[(size_t)row * N + col] + v;
        } else if constexpr (EPI == 2) {
          const float gel = 0.5f * v * (1.0f + erff(v * 0.70710678118f));
          Ch[(size_t)row * N + col] = (half_t)(gel * gd[row * 16 + (col >> 8)]);
        } else {
          Cf[(size_t)row * N + col] = res[(size_t)row * N + col] + v;
        }
      }
    }
  }
}

// ---------------- fused flash attention ----------------
// grid (8 qtiles, 512 = b*16+h); block 256 (4 waves x 16 q-rows)
__global__ __launch_bounds__(256) void attn_fwd(const half_t* __restrict__ qkv,
                                                half_t* __restrict__ ctx) {
  const int bh = blockIdx.y;
  const int b = bh >> 4, h = bh & 15;
  const int qbase = blockIdx.x * 64;
  const int tid = threadIdx.x;
  const int wave = tid >> 6, lane = tid & 63;
  const int l15 = lane & 15, g = lane >> 4;
  __shared__ half_t K_s[2][32 * 64];
  __shared__ half_t Vt_s[2][64 * 32];
  __shared__ half_t P_s[4][16 * 32];

  const size_t qrow = (size_t)(b * 512 + qbase + wave * 16 + l15);
  h8 aq0 = *(const h8*)(qkv + qrow * 3072 + h * 64 + g * 8);
  h8 aq1 = *(const h8*)(qkv + qrow * 3072 + h * 64 + 32 + g * 8);
  aq0 = aq0 * (half_t)0.125f;  // fold 1/sqrt(dh) into Q
  aq1 = aq1 * (half_t)0.125f;

  float mr[4], sr[4];
  f32x4 o[4] = {};
#pragma unroll
  for (int r = 0; r < 4; ++r) { mr[r] = -1e30f; sr[r] = 0.0f; }

  const int key = tid >> 3, c0 = (tid & 7) << 3;
  const half_t* kbase = qkv + 1024 + h * 64 + c0;
  const half_t* vbase = qkv + 2048 + h * 64 + c0;

  for (int kt = 0; kt < 16; ++kt) {
    const int buf = kt & 1;
    const size_t krow = (size_t)(b * 512 + kt * 32 + key);
    const h8 kv = *(const h8*)(kbase + krow * 3072);
    *(h8*)(&K_s[buf][key * 64 + c0]) = kv;
    const h8 vv = *(const h8*)(vbase + krow * 3072);
#pragma unroll
    for (int j = 0; j < 8; ++j) Vt_s[buf][(c0 + j) * 32 + key] = vv[j];
    __syncthreads();

    f32x4 s0 = {0.f, 0.f, 0.f, 0.f}, s1 = {0.f, 0.f, 0.f, 0.f};
    s0 = mfma16(aq0, *(const h8*)(&K_s[buf][l15 * 64 + g * 8]), s0);
    s0 = mfma16(aq1, *(const h8*)(&K_s[buf][l15 * 64 + 32 + g * 8]), s0);
    s1 = mfma16(aq0, *(const h8*)(&K_s[buf][(16 + l15) * 64 + g * 8]), s1);
    s1 = mfma16(aq1, *(const h8*)(&K_s[buf][(16 + l15) * 64 + 32 + g * 8]), s1);

#pragma unroll
    for (int r = 0; r < 4; ++r) {
      const float a0 = s0[r], a1 = s1[r];
      float tm = fmaxf(a0, a1);
#pragma unroll
      for (int msk = 1; msk < 16; msk <<= 1) tm = fmaxf(tm, __shfl_xor(tm, msk));
      const float mnew = fmaxf(mr[r], tm);
      const float alpha = __expf(mr[r] - mnew);
      const float p0 = __expf(a0 - mnew), p1 = __expf(a1 - mnew);
      float rs = p0 + p1;
#pragma unroll
      for (int msk = 1; msk < 16; msk <<= 1) rs += __shfl_xor(rs, msk);
      sr[r] = sr[r] * alpha + rs;
      mr[r] = mnew;
#pragma unroll
      for (int d = 0; d < 4; ++d) o[d][r] *= alpha;
      P_s[wave][(g * 4 + r) * 32 + l15] = (half_t)p0;
      P_s[wave][(g * 4 + r) * 32 + 16 + l15] = (half_t)p1;
    }
    __syncthreads();

    const h8 pa = *(const h8*)(&P_s[wave][l15 * 32 + g * 8]);
#pragma unroll
    for (int d = 0; d < 4; ++d)
      o[d] = mfma16(pa, *(const h8*)(&Vt_s[buf][(d * 16 + l15) * 32 + g * 8]), o[d]);
  }
#pragma unroll
  for (int d = 0; d < 4; ++d) {
#pragma unroll
    for (int r = 0; r < 4; ++r) {
      const size_t row = (size_t)(b * 512 + qbase + wave * 16 + g * 4 + r);
      ctx[row * 1024 + h * 64 + d * 16 + l15] = (half_t)(o[d][r] / sr[r]);
    }
  }
}

// ---------------- gating: logits, softmax, probs, top-8, gate_dense, mean_p ----------------
__global__ __launch_bounds__(256) void gate_fwd(const half_t* __restrict__ h3,
                                                const float* __restrict__ gate_w,
                                                const int* __restrict__ task_id,
                                                float* __restrict__ probs,
                                                float* __restrict__ gd,
                                                float* __restrict__ mp) {
  const int tid = threadIdx.x, wave = tid >> 6, lane = tid & 63;
  const float* gw = gate_w + (size_t)task_id[0] * 16384;
  __shared__ float mp_part[16];
  if (tid < 16) mp_part[tid] = 0.0f;
  __syncthreads();
  float mpl[16];
#pragma unroll
  for (int e = 0; e < 16; ++e) mpl[e] = 0.0f;
  const int t0 = blockIdx.x * 64 + wave * 16;
  for (int tt = 0; tt < 16; ++tt) {
    const int t = t0 + tt;
    float acc[16];
#pragma unroll
    for (int e = 0; e < 16; ++e) acc[e] = 0.0f;
#pragma unroll
    for (int i = 0; i < 16; ++i) {
      const int d = i * 64 + lane;
      const float hv = (float)h3[(size_t)t * 1024 + d];
      const float4* gp = (const float4*)(gw + d * 16);
      const float4 g0 = gp[0], g1 = gp[1], g2 = gp[2], g3 = gp[3];
      acc[0] = fmaf(hv, g0.x, acc[0]);  acc[1] = fmaf(hv, g0.y, acc[1]);
      acc[2] = fmaf(hv, g0.z, acc[2]);  acc[3] = fmaf(hv, g0.w, acc[3]);
      acc[4] = fmaf(hv, g1.x, acc[4]);  acc[5] = fmaf(hv, g1.y, acc[5]);
      acc[6] = fmaf(hv, g1.z, acc[6]);  acc[7] = fmaf(hv, g1.w, acc[7]);
      acc[8] = fmaf(hv, g2.x, acc[8]);  acc[9] = fmaf(hv, g2.y, acc[9]);
      acc[10] = fmaf(hv, g2.z, acc[10]); acc[11] = fmaf(hv, g2.w, acc[11]);
      acc[12] = fmaf(hv, g3.x, acc[12]); acc[13] = fmaf(hv, g3.y, acc[13]);
      acc[14] = fmaf(hv, g3.z, acc[14]); acc[15] = fmaf(hv, g3.w, acc[15]);
    }
#pragma unroll
    for (int msk = 32; msk >= 1; msk >>= 1)
#pragma unroll
      for (int e = 0; e < 16; ++e) acc[e] += __shfl_xor(acc[e], msk);
    float mx = acc[0];
#pragma unroll
    for (int e = 1; e < 16; ++e) mx = fmaxf(mx, acc[e]);
    float p[16];
    float sum = 0.0f;
#pragma unroll
    for (int e = 0; e < 16; ++e) { p[e] = __expf(acc[e] - mx); sum += p[e]; }
    const float inv = 1.0f / sum;
#pragma unroll
    for (int e = 0; e < 16; ++e) p[e] *= inv;
    float myp = p[0];
#pragma unroll
    for (int e = 1; e < 16; ++e) myp = (lane == e) ? p[e] : myp;
    if (lane < 16) probs[(size_t)t * 16 + lane] = myp;
#pragma unroll
    for (int e = 0; e < 16; ++e) mpl[e] += p[e];
    // top-8 selection (ties -> lowest index, matching lax.top_k)
    float v[16];
#pragma unroll
    for (int e = 0; e < 16; ++e) v[e] = p[e];
    float topv[8];
    int topi[8];
#pragma unroll
    for (int k = 0; k < 8; ++k) {
      float vm = -1.0f;
      int im = 0;
#pragma unroll
      for (int e = 0; e < 16; ++e) {
        const bool gt = v[e] > vm;
        vm = gt ? v[e] : vm;
        im = gt ? e : im;
      }
      topv[k] = vm; topi[k] = im;
#pragma unroll
      for (int e = 0; e < 16; ++e) v[e] = (e == im) ? -1.0f : v[e];
    }
    float ts = 1e-6f;
#pragma unroll
    for (int k = 0; k < 8; ++k) ts += topv[k];
    const float tinv = 1.0f / ts;
    float gval = 0.0f;
#pragma unroll
    for (int k = 0; k < 8; ++k) gval = (topi[k] == lane) ? topv[k] * tinv : gval;
    if (lane < 16) gd[(size_t)t * 16 + lane] = gval;
  }
  if (lane == 0) {
#pragma unroll
    for (int e = 0; e < 16; ++e) atomicAdd(&mp_part[e], mpl[e]);
  }
  __syncthreads();
  if (tid < 16) atomicAdd(&mp[tid], mp_part[tid]);
}

// ---------------- aux loss ----------------
__global__ void aux_fwd(const float* __restrict__ mp, float* __restrict__ out) {
  if (threadIdx.x == 0) {
    float a = 0.0f;
    for (int e = 0; e < 16; ++e) {
      const float m = mp[e] * (1.0f / 16384.0f);
      a += m * logf(m + 1e-6f);
    }
    out[0] = 5e-4f * a;
  }
}

// ---------------- d_out += gate_dense @ b2 ----------------
__global__ __launch_bounds__(256) void bias2_add(const float* __restrict__ gd,
                                                 const float* __restrict__ b2,
                                                 float* __restrict__ out) {
  const int t = blockIdx.x, tid = threadIdx.x;
  __shared__ float gds[16];
  if (tid < 16) gds[tid] = gd[(size_t)t * 16 + tid];
  __syncthreads();
  float4 v = *(const float4*)(out + (size_t)t * 1024 + tid * 4);
#pragma unroll
  for (int e = 0; e < 16; ++e) {
    const float gv = gds[e];
    const float4 bv = *(const float4*)(b2 + e * 1024 + tid * 4);
    v.x = fmaf(gv, bv.x, v.x);
    v.y = fmaf(gv, bv.y, v.y);
    v.z = fmaf(gv, bv.z, v.z);
    v.w = fmaf(gv, bv.w, v.w);
  }
  *(float4*)(out + (size_t)t * 1024 + tid * 4) = v;
}

extern "C" void kernel_launch(void* const* d_in, const int* in_sizes, int n_in,
                              void* d_out, int out_size, void* d_ws, size_t ws_size,
                              hipStream_t stream) {
  const float* tgt = (const float*)d_in[0];
  const float* ln1_g = (const float*)d_in[2];
  const float* ln1_b = (const float*)d_in[3];
  const float* ln3_g = (const float*)d_in[4];
  const float* ln3_b = (const float*)d_in[5];
  const float* Wqkv = (const float*)d_in[6];
  const float* bqkv = (const float*)d_in[7];
  const float* Wout = (const float*)d_in[8];
  const float* bout = (const float*)d_in[9];
  const float* gate_w = (const float*)d_in[10];
  const float* w1 = (const float*)d_in[11];
  const float* b1 = (const float*)d_in[12];
  const float* w2 = (const float*)d_in[13];
  const float* b2 = (const float*)d_in[14];
  const int* task = (const int*)d_in[15];
  float* out = (float*)d_out;
  char* ws = (char*)d_ws;

  // ws layout (bytes):
  half_t* h = (half_t*)(ws + 0ull);                   // 32MB  [T,1024] (h, later h3)
  half_t* qkv = (half_t*)(ws + 33554432ull);          // 96MB  [T,3072]
  half_t* ctx = (half_t*)(ws + 134217728ull);         // 32MB  [T,1024]
  half_t* uw = (half_t*)(ws + 33554432ull);           // 128MB [T,4096] overlays qkv+ctx
  half_t* wqkv_h = (half_t*)(ws + 167772160ull);      // 6MB
  half_t* wout_h = (half_t*)(ws + 174063616ull);      // 2MB
  half_t* w1t = (half_t*)(ws + 176160768ull);         // 8MB
  half_t* w2t = (half_t*)(ws + 184549376ull);         // 8MB
  float* gd = (float*)(ws + 192937984ull);            // 1MB [T,16]
  float* mp = (float*)(ws + 193986560ull);            // 64B [16]

  hipMemsetAsync(mp, 0, 64, stream);
  cvt_f2h<<<3072, 256, 0, stream>>>(Wqkv, wqkv_h, 3145728);
  cvt_f2h<<<1024, 256, 0, stream>>>(Wout, wout_h, 1048576);
  tr_w1<<<dim3(8, 32, 16), 256, 0, stream>>>(w1, w1t);
  tr_w2<<<dim3(32, 8, 16), 256, 0, stream>>>(w2, w2t);

  ln_fwd<<<16384, 256, 0, stream>>>(tgt, ln1_g, ln1_b, h);
  // QKV: M=16384, N=3072, K=1024 -> grid 12*64=768
  gemm256<0><<<768, 512, 0, stream>>>(h, wqkv_h, 3072, 1024, 12, bqkv, nullptr, nullptr, qkv, nullptr);
  attn_fwd<<<dim3(8, 512), 256, 0, stream>>>(qkv, ctx);
  // out-proj: N=1024, K=1024 -> grid 4*64=256
  gemm256<1><<<256, 512, 0, stream>>>(ctx, wout_h, 1024, 1024, 4, bout, tgt, nullptr, nullptr, out);

  ln_fwd<<<16384, 256, 0, stream>>>(out, ln3_g, ln3_b, h);
  gate_fwd<<<256, 256, 0, stream>>>(h, gate_w, task, out + 16777217, gd, mp);
  aux_fwd<<<1, 64, 0, stream>>>(mp, out + 16777216);
  bias2_add<<<16384, 256, 0, stream>>>(gd, b2, out);
  // MoE up: N=4096, K=1024 -> grid 16*64=1024
  gemm256<2><<<1024, 512, 0, stream>>>(h, w1t, 4096, 1024, 16, b1, nullptr, gd, uw, nullptr);
  // MoE down: N=1024, K=4096 -> grid 4*64=256
  gemm256<3><<<256, 512, 0, stream>>>(uw, w2t, 1024, 4096, 4, nullptr, out, nullptr, nullptr, out);
}

// Round 4
// 1159.854 us; speedup vs baseline: 1.1873x; 1.1018x over previous
//
#include <hip/hip_runtime.h>

typedef float f32x4 __attribute__((ext_vector_type(4)));
typedef _Float16 half_t;
typedef _Float16 h8 __attribute__((ext_vector_type(8)));
typedef _Float16 h4 __attribute__((ext_vector_type(4)));

__device__ __forceinline__ f32x4 mfma16(h8 a, h8 b, f32x4 c) {
  return __builtin_amdgcn_mfma_f32_16x16x32_f16(a, b, c, 0, 0, 0);
}

// ---------------- LayerNorm (f32 in -> f16 out) ----------------
__global__ __launch_bounds__(256) void ln_fwd(const float* __restrict__ x,
                                              const float* __restrict__ g,
                                              const float* __restrict__ b,
                                              half_t* __restrict__ out) {
  const int row = blockIdx.x;
  const int tid = threadIdx.x;
  const float4 v = ((const float4*)(x + (size_t)row * 1024))[tid];
  float s = v.x + v.y + v.z + v.w;
  float q = v.x * v.x + v.y * v.y + v.z * v.z + v.w * v.w;
#pragma unroll
  for (int m = 1; m < 64; m <<= 1) { s += __shfl_xor(s, m); q += __shfl_xor(q, m); }
  __shared__ float red[8];
  const int wave = tid >> 6, lane = tid & 63;
  if (lane == 0) { red[wave] = s; red[wave + 4] = q; }
  __syncthreads();
  s = red[0] + red[1] + red[2] + red[3];
  q = red[4] + red[5] + red[6] + red[7];
  const float mean = s * (1.0f / 1024.0f);
  const float var = q * (1.0f / 1024.0f) - mean * mean;
  const float rstd = rsqrtf(var + 1e-5f);
  const float4 gv = ((const float4*)g)[tid];
  const float4 bv = ((const float4*)b)[tid];
  h4 o;
  o[0] = (half_t)((v.x - mean) * rstd * gv.x + bv.x);
  o[1] = (half_t)((v.y - mean) * rstd * gv.y + bv.y);
  o[2] = (half_t)((v.z - mean) * rstd * gv.z + bv.z);
  o[3] = (half_t)((v.w - mean) * rstd * gv.w + bv.w);
  *(h4*)(out + (size_t)row * 1024 + tid * 4) = o;
}

// ---------------- f32 -> f16 convert ----------------
__global__ __launch_bounds__(256) void cvt_f2h(const float* __restrict__ in,
                                               half_t* __restrict__ out, int n) {
  const int i = (blockIdx.x * 256 + threadIdx.x) * 4;
  if (i < n) {
    const float4 v = *(const float4*)(in + i);
    h4 o = {(half_t)v.x, (half_t)v.y, (half_t)v.z, (half_t)v.w};
    *(h4*)(out + i) = o;
  }
}

// ---------------- w1 [E,D,H] -> w1t [(E*H), D]  (f16) ----------------
__global__ __launch_bounds__(256) void tr_w1(const float* __restrict__ w1,
                                             half_t* __restrict__ w1t) {
  __shared__ float tile[32][33];
  const int e = blockIdx.z;
  const int tx = threadIdx.x & 31, ty = threadIdx.x >> 5;
  const int hh = blockIdx.x * 32 + tx;
#pragma unroll
  for (int i = 0; i < 4; ++i) {
    const int d = blockIdx.y * 32 + ty + i * 8;
    tile[ty + i * 8][tx] = w1[(size_t)e * 262144 + (size_t)d * 256 + hh];
  }
  __syncthreads();
#pragma unroll
  for (int i = 0; i < 4; ++i) {
    const int hho = blockIdx.x * 32 + ty + i * 8;
    const int k = blockIdx.y * 32 + tx;
    w1t[(size_t)(e * 256 + hho) * 1024 + k] = (half_t)tile[tx][ty + i * 8];
  }
}

// ---------------- w2 [E,H,D] -> w2t [D, (E*H)]  (f16) ----------------
__global__ __launch_bounds__(256) void tr_w2(const float* __restrict__ w2,
                                             half_t* __restrict__ w2t) {
  __shared__ float tile[32][33];
  const int e = blockIdx.z;
  const int tx = threadIdx.x & 31, ty = threadIdx.x >> 5;
  const int d_in = blockIdx.x * 32 + tx;
#pragma unroll
  for (int i = 0; i < 4; ++i) {
    const int hh = blockIdx.y * 32 + ty + i * 8;
    tile[ty + i * 8][tx] = w2[(size_t)e * 262144 + (size_t)hh * 1024 + d_in];
  }
  __syncthreads();
#pragma unroll
  for (int i = 0; i < 4; ++i) {
    const int d = blockIdx.x * 32 + ty + i * 8;
    const int hh = blockIdx.y * 32 + tx;
    w2t[(size_t)d * 4096 + e * 256 + hh] = (half_t)tile[tx][ty + i * 8];
  }
}

// ---------------- 256x256 MFMA GEMM, A[M,K] x Bt[N,K]^T ----------------
// 8 waves (2M x 4N), per-wave 128x64 out, BK=64, dbuf 2 K-tiles (128 KiB LDS).
// 2 raw barriers per K-tile, counted vmcnt(8), compiler-scheduled interior,
// XOR-swizzled LDS (both-sides: pre-swizzled global source + swizzled read).
// EPI 0: Ch = f16(acc + bias)                          (QKV)
// EPI 1: Cf = res + acc + bias                         (out-proj + residual)
// EPI 2: Ch = f16(gelu(acc + bias) * gd[row, col>>8])  (MoE up)
// EPI 3: Cf = res + acc                                (MoE down accumulate)
template <int EPI>
__global__ __launch_bounds__(512, 2) void gemm256(const half_t* __restrict__ A,
                                                  const half_t* __restrict__ Bt,
                                                  int N, int K, int nbx,
                                                  const float* __restrict__ bias,
                                                  const float* __restrict__ res,
                                                  const float* __restrict__ gd,
                                                  half_t* __restrict__ Ch,
                                                  float* __restrict__ Cf) {
  __shared__ half_t lds[2][2][256 * 64];  // [slot][A/B][row*64 + col]
  const int tid = threadIdx.x;
  const int wave = tid >> 6, lane = tid & 63;
  const int l15 = lane & 15, g = lane >> 4;
  const int wr = wave >> 2, wc = wave & 3;

  // XCD-aware bijective swizzle (all grids here are divisible by 8)
  const int nwg = gridDim.x;
  const int bid = blockIdx.x;
  const int swz = (bid & 7) * (nwg >> 3) + (bid >> 3);
  const int bx = swz % nbx, by = swz / nbx;

  const int NT = K >> 6;
  f32x4 acc[8][4] = {};

  // stage one K-tile (A 256x64 + B 256x64) into slot kt&1, linear LDS dest,
  // global source column pre-permuted by slot^(row&7) (16B granules).
  auto stageAB = [&](int kt) {
    const int bt = kt & 1;
    const size_t abase = (size_t)(by * 256) * K + kt * 64;
    const size_t bbase = (size_t)(bx * 256) * K + kt * 64;
#pragma unroll
    for (int j = 0; j < 4; ++j) {
      const int c = tid + j * 512;
      const int row = c >> 3, sl = c & 7;
      const int col = (sl ^ (row & 7)) << 3;
      __builtin_amdgcn_global_load_lds(
          (const __attribute__((address_space(1))) void*)(A + abase + (size_t)row * K + col),
          (__attribute__((address_space(3))) void*)(&lds[bt][0][c * 8]), 16, 0, 0);
      __builtin_amdgcn_global_load_lds(
          (const __attribute__((address_space(1))) void*)(Bt + bbase + (size_t)row * K + col),
          (__attribute__((address_space(3))) void*)(&lds[bt][1][c * 8]), 16, 0, 0);
    }
  };

  stageAB(0);
  for (int kt = 0; kt < NT; ++kt) {
    const int bt = kt & 1;
    if (kt + 1 < NT) {
      stageAB(kt + 1);
      asm volatile("s_waitcnt vmcnt(8)" ::: "memory");  // tile kt staged; kt+1 in flight
    } else {
      asm volatile("s_waitcnt vmcnt(0)" ::: "memory");
    }
    __builtin_amdgcn_s_barrier();  // slot bt visible to all waves

    // ---- full K-tile compute, compiler-scheduled (fine-grained lgkmcnt) ----
    h8 a0[4][2], a1[4][2], b0[2][2], b1[2][2];
#pragma unroll
    for (int m4 = 0; m4 < 4; ++m4)
#pragma unroll
      for (int kk = 0; kk < 2; ++kk) {
        const int row = wr * 128 + m4 * 16 + l15;
        const int sl = ((kk << 2) | g) ^ (row & 7);
        a0[m4][kk] = *(const h8*)(&lds[bt][0][row * 64 + sl * 8]);
      }
#pragma unroll
    for (int n2 = 0; n2 < 2; ++n2)
#pragma unroll
      for (int kk = 0; kk < 2; ++kk) {
        const int rowb0 = wc * 64 + n2 * 16 + l15;
        const int slb0 = ((kk << 2) | g) ^ (rowb0 & 7);
        b0[n2][kk] = *(const h8*)(&lds[bt][1][rowb0 * 64 + slb0 * 8]);
        const int rowb1 = wc * 64 + 32 + n2 * 16 + l15;
        const int slb1 = ((kk << 2) | g) ^ (rowb1 & 7);
        b1[n2][kk] = *(const h8*)(&lds[bt][1][rowb1 * 64 + slb1 * 8]);
      }
#pragma unroll
    for (int m4 = 0; m4 < 4; ++m4)
#pragma unroll
      for (int n2 = 0; n2 < 2; ++n2)
#pragma unroll
        for (int kk = 0; kk < 2; ++kk) {
          acc[m4][n2] = mfma16(a0[m4][kk], b0[n2][kk], acc[m4][n2]);
          acc[m4][2 + n2] = mfma16(a0[m4][kk], b1[n2][kk], acc[m4][2 + n2]);
        }
#pragma unroll
    for (int m4 = 0; m4 < 4; ++m4)
#pragma unroll
      for (int kk = 0; kk < 2; ++kk) {
        const int row = wr * 128 + 64 + m4 * 16 + l15;
        const int sl = ((kk << 2) | g) ^ (row & 7);
        a1[m4][kk] = *(const h8*)(&lds[bt][0][row * 64 + sl * 8]);
      }
#pragma unroll
    for (int m4 = 0; m4 < 4; ++m4)
#pragma unroll
      for (int n2 = 0; n2 < 2; ++n2)
#pragma unroll
        for (int kk = 0; kk < 2; ++kk) {
          acc[4 + m4][n2] = mfma16(a1[m4][kk], b0[n2][kk], acc[4 + m4][n2]);
          acc[4 + m4][2 + n2] = mfma16(a1[m4][kk], b1[n2][kk], acc[4 + m4][2 + n2]);
        }

    // all reads of slot bt drained before anyone stages over it next iter
    asm volatile("s_waitcnt lgkmcnt(0)" ::: "memory");
    __builtin_amdgcn_s_barrier();
  }

  // epilogue
#pragma unroll
  for (int m = 0; m < 8; ++m) {
#pragma unroll
    for (int n = 0; n < 4; ++n) {
      const int col = bx * 256 + wc * 64 + n * 16 + l15;
      float bv = 0.0f;
      if constexpr (EPI != 3) bv = bias[col];
#pragma unroll
      for (int r = 0; r < 4; ++r) {
        const int row = by * 256 + wr * 128 + m * 16 + g * 4 + r;
        const float v = acc[m][n][r] + bv;
        if constexpr (EPI == 0) {
          Ch[(size_t)row * N + col] = (half_t)v;
        } else if constexpr (EPI == 1) {
          Cf[(size_t)row * N + col] = res[(size_t)row * N + col] + v;
        } else if constexpr (EPI == 2) {
          const float gel = 0.5f * v * (1.0f + erff(v * 0.70710678118f));
          Ch[(size_t)row * N + col] = (half_t)(gel * gd[row * 16 + (col >> 8)]);
        } else {
          Cf[(size_t)row * N + col] = res[(size_t)row * N + col] + v;
        }
      }
    }
  }
}

// ---------------- fused flash attention ----------------
// grid (8 qtiles, 512 = b*16+h); block 256 (4 waves x 16 q-rows)
__global__ __launch_bounds__(256) void attn_fwd(const half_t* __restrict__ qkv,
                                                half_t* __restrict__ ctx) {
  const int bh = blockIdx.y;
  const int b = bh >> 4, h = bh & 15;
  const int qbase = blockIdx.x * 64;
  const int tid = threadIdx.x;
  const int wave = tid >> 6, lane = tid & 63;
  const int l15 = lane & 15, g = lane >> 4;
  __shared__ half_t K_s[2][32 * 64];
  __shared__ half_t Vt_s[2][64 * 32];
  __shared__ half_t P_s[4][16 * 32];

  const size_t qrow = (size_t)(b * 512 + qbase + wave * 16 + l15);
  h8 aq0 = *(const h8*)(qkv + qrow * 3072 + h * 64 + g * 8);
  h8 aq1 = *(const h8*)(qkv + qrow * 3072 + h * 64 + 32 + g * 8);
  aq0 = aq0 * (half_t)0.125f;  // fold 1/sqrt(dh) into Q
  aq1 = aq1 * (half_t)0.125f;

  float mr[4], sr[4];
  f32x4 o[4] = {};
#pragma unroll
  for (int r = 0; r < 4; ++r) { mr[r] = -1e30f; sr[r] = 0.0f; }

  const int key = tid >> 3, c0 = (tid & 7) << 3;
  const half_t* kbase = qkv + 1024 + h * 64 + c0;
  const half_t* vbase = qkv + 2048 + h * 64 + c0;

  for (int kt = 0; kt < 16; ++kt) {
    const int buf = kt & 1;
    const size_t krow = (size_t)(b * 512 + kt * 32 + key);
    const h8 kv = *(const h8*)(kbase + krow * 3072);
    *(h8*)(&K_s[buf][key * 64 + c0]) = kv;
    const h8 vv = *(const h8*)(vbase + krow * 3072);
#pragma unroll
    for (int j = 0; j < 8; ++j) Vt_s[buf][(c0 + j) * 32 + key] = vv[j];
    __syncthreads();

    f32x4 s0 = {0.f, 0.f, 0.f, 0.f}, s1 = {0.f, 0.f, 0.f, 0.f};
    s0 = mfma16(aq0, *(const h8*)(&K_s[buf][l15 * 64 + g * 8]), s0);
    s0 = mfma16(aq1, *(const h8*)(&K_s[buf][l15 * 64 + 32 + g * 8]), s0);
    s1 = mfma16(aq0, *(const h8*)(&K_s[buf][(16 + l15) * 64 + g * 8]), s1);
    s1 = mfma16(aq1, *(const h8*)(&K_s[buf][(16 + l15) * 64 + 32 + g * 8]), s1);

#pragma unroll
    for (int r = 0; r < 4; ++r) {
      const float a0 = s0[r], a1 = s1[r];
      float tm = fmaxf(a0, a1);
#pragma unroll
      for (int msk = 1; msk < 16; msk <<= 1) tm = fmaxf(tm, __shfl_xor(tm, msk));
      const float mnew = fmaxf(mr[r], tm);
      const float alpha = __expf(mr[r] - mnew);
      const float p0 = __expf(a0 - mnew), p1 = __expf(a1 - mnew);
      float rs = p0 + p1;
#pragma unroll
      for (int msk = 1; msk < 16; msk <<= 1) rs += __shfl_xor(rs, msk);
      sr[r] = sr[r] * alpha + rs;
      mr[r] = mnew;
#pragma unroll
      for (int d = 0; d < 4; ++d) o[d][r] *= alpha;
      P_s[wave][(g * 4 + r) * 32 + l15] = (half_t)p0;
      P_s[wave][(g * 4 + r) * 32 + 16 + l15] = (half_t)p1;
    }
    __syncthreads();

    const h8 pa = *(const h8*)(&P_s[wave][l15 * 32 + g * 8]);
#pragma unroll
    for (int d = 0; d < 4; ++d)
      o[d] = mfma16(pa, *(const h8*)(&Vt_s[buf][(d * 16 + l15) * 32 + g * 8]), o[d]);
  }
#pragma unroll
  for (int d = 0; d < 4; ++d) {
#pragma unroll
    for (int r = 0; r < 4; ++r) {
      const size_t row = (size_t)(b * 512 + qbase + wave * 16 + g * 4 + r);
      ctx[row * 1024 + h * 64 + d * 16 + l15] = (half_t)(o[d][r] / sr[r]);
    }
  }
}

// ---------------- gating: logits, softmax, probs, top-8, gate_dense, mean_p ----------------
__global__ __launch_bounds__(256) void gate_fwd(const half_t* __restrict__ h3,
                                                const float* __restrict__ gate_w,
                                                const int* __restrict__ task_id,
                                                float* __restrict__ probs,
                                                float* __restrict__ gd,
                                                float* __restrict__ mp) {
  const int tid = threadIdx.x, wave = tid >> 6, lane = tid & 63;
  const float* gw = gate_w + (size_t)task_id[0] * 16384;
  __shared__ float mp_part[16];
  if (tid < 16) mp_part[tid] = 0.0f;
  __syncthreads();
  float mpl[16];
#pragma unroll
  for (int e = 0; e < 16; ++e) mpl[e] = 0.0f;
  const int t0 = blockIdx.x * 64 + wave * 16;
  for (int tt = 0; tt < 16; ++tt) {
    const int t = t0 + tt;
    float acc[16];
#pragma unroll
    for (int e = 0; e < 16; ++e) acc[e] = 0.0f;
#pragma unroll
    for (int i = 0; i < 16; ++i) {
      const int d = i * 64 + lane;
      const float hv = (float)h3[(size_t)t * 1024 + d];
      const float4* gp = (const float4*)(gw + d * 16);
      const float4 g0 = gp[0], g1 = gp[1], g2 = gp[2], g3 = gp[3];
      acc[0] = fmaf(hv, g0.x, acc[0]);  acc[1] = fmaf(hv, g0.y, acc[1]);
      acc[2] = fmaf(hv, g0.z, acc[2]);  acc[3] = fmaf(hv, g0.w, acc[3]);
      acc[4] = fmaf(hv, g1.x, acc[4]);  acc[5] = fmaf(hv, g1.y, acc[5]);
      acc[6] = fmaf(hv, g1.z, acc[6]);  acc[7] = fmaf(hv, g1.w, acc[7]);
      acc[8] = fmaf(hv, g2.x, acc[8]);  acc[9] = fmaf(hv, g2.y, acc[9]);
      acc[10] = fmaf(hv, g2.z, acc[10]); acc[11] = fmaf(hv, g2.w, acc[11]);
      acc[12] = fmaf(hv, g3.x, acc[12]); acc[13] = fmaf(hv, g3.y, acc[13]);
      acc[14] = fmaf(hv, g3.z, acc[14]); acc[15] = fmaf(hv, g3.w, acc[15]);
    }
#pragma unroll
    for (int msk = 32; msk >= 1; msk >>= 1)
#pragma unroll
      for (int e = 0; e < 16; ++e) acc[e] += __shfl_xor(acc[e], msk);
    float mx = acc[0];
#pragma unroll
    for (int e = 1; e < 16; ++e) mx = fmaxf(mx, acc[e]);
    float p[16];
    float sum = 0.0f;
#pragma unroll
    for (int e = 0; e < 16; ++e) { p[e] = __expf(acc[e] - mx); sum += p[e]; }
    const float inv = 1.0f / sum;
#pragma unroll
    for (int e = 0; e < 16; ++e) p[e] *= inv;
    float myp = p[0];
#pragma unroll
    for (int e = 1; e < 16; ++e) myp = (lane == e) ? p[e] : myp;
    if (lane < 16) probs[(size_t)t * 16 + lane] = myp;
#pragma unroll
    for (int e = 0; e < 16; ++e) mpl[e] += p[e];
    // top-8 selection (ties -> lowest index, matching lax.top_k)
    float v[16];
#pragma unroll
    for (int e = 0; e < 16; ++e) v[e] = p[e];
    float topv[8];
    int topi[8];
#pragma unroll
    for (int k = 0; k < 8; ++k) {
      float vm = -1.0f;
      int im = 0;
#pragma unroll
      for (int e = 0; e < 16; ++e) {
        const bool gt = v[e] > vm;
        vm = gt ? v[e] : vm;
        im = gt ? e : im;
      }
      topv[k] = vm; topi[k] = im;
#pragma unroll
      for (int e = 0; e < 16; ++e) v[e] = (e == im) ? -1.0f : v[e];
    }
    float ts = 1e-6f;
#pragma unroll
    for (int k = 0; k < 8; ++k) ts += topv[k];
    const float tinv = 1.0f / ts;
    float gval = 0.0f;
#pragma unroll
    for (int k = 0; k < 8; ++k) gval = (topi[k] == lane) ? topv[k] * tinv : gval;
    if (lane < 16) gd[(size_t)t * 16 + lane] = gval;
  }
  if (lane == 0) {
#pragma unroll
    for (int e = 0; e < 16; ++e) atomicAdd(&mp_part[e], mpl[e]);
  }
  __syncthreads();
  if (tid < 16) atomicAdd(&mp[tid], mp_part[tid]);
}

// ---------------- aux loss ----------------
__global__ void aux_fwd(const float* __restrict__ mp, float* __restrict__ out) {
  if (threadIdx.x == 0) {
    float a = 0.0f;
    for (int e = 0; e < 16; ++e) {
      const float m = mp[e] * (1.0f / 16384.0f);
      a += m * logf(m + 1e-6f);
    }
    out[0] = 5e-4f * a;
  }
}

// ---------------- d_out += gate_dense @ b2 ----------------
__global__ __launch_bounds__(256) void bias2_add(const float* __restrict__ gd,
                                                 const float* __restrict__ b2,
                                                 float* __restrict__ out) {
  const int t = blockIdx.x, tid = threadIdx.x;
  __shared__ float gds[16];
  if (tid < 16) gds[tid] = gd[(size_t)t * 16 + tid];
  __syncthreads();
  float4 v = *(const float4*)(out + (size_t)t * 1024 + tid * 4);
#pragma unroll
  for (int e = 0; e < 16; ++e) {
    const float gv = gds[e];
    const float4 bv = *(const float4*)(b2 + e * 1024 + tid * 4);
    v.x = fmaf(gv, bv.x, v.x);
    v.y = fmaf(gv, bv.y, v.y);
    v.z = fmaf(gv, bv.z, v.z);
    v.w = fmaf(gv, bv.w, v.w);
  }
  *(float4*)(out + (size_t)t * 1024 + tid * 4) = v;
}

extern "C" void kernel_launch(void* const* d_in, const int* in_sizes, int n_in,
                              void* d_out, int out_size, void* d_ws, size_t ws_size,
                              hipStream_t stream) {
  const float* tgt = (const float*)d_in[0];
  const float* ln1_g = (const float*)d_in[2];
  const float* ln1_b = (const float*)d_in[3];
  const float* ln3_g = (const float*)d_in[4];
  const float* ln3_b = (const float*)d_in[5];
  const float* Wqkv = (const float*)d_in[6];
  const float* bqkv = (const float*)d_in[7];
  const float* Wout = (const float*)d_in[8];
  const float* bout = (const float*)d_in[9];
  const float* gate_w = (const float*)d_in[10];
  const float* w1 = (const float*)d_in[11];
  const float* b1 = (const float*)d_in[12];
  const float* w2 = (const float*)d_in[13];
  const float* b2 = (const float*)d_in[14];
  const int* task = (const int*)d_in[15];
  float* out = (float*)d_out;
  char* ws = (char*)d_ws;

  // ws layout (bytes):
  half_t* h = (half_t*)(ws + 0ull);                   // 32MB  [T,1024] (h, later h3)
  half_t* qkv = (half_t*)(ws + 33554432ull);          // 96MB  [T,3072]
  half_t* ctx = (half_t*)(ws + 134217728ull);         // 32MB  [T,1024]
  half_t* uw = (half_t*)(ws + 33554432ull);           // 128MB [T,4096] overlays qkv+ctx
  half_t* wqkv_h = (half_t*)(ws + 167772160ull);      // 6MB
  half_t* wout_h = (half_t*)(ws + 174063616ull);      // 2MB
  half_t* w1t = (half_t*)(ws + 176160768ull);         // 8MB
  half_t* w2t = (half_t*)(ws + 184549376ull);         // 8MB
  float* gd = (float*)(ws + 192937984ull);            // 1MB [T,16]
  float* mp = (float*)(ws + 193986560ull);            // 64B [16]

  hipMemsetAsync(mp, 0, 64, stream);
  cvt_f2h<<<3072, 256, 0, stream>>>(Wqkv, wqkv_h, 3145728);
  cvt_f2h<<<1024, 256, 0, stream>>>(Wout, wout_h, 1048576);
  tr_w1<<<dim3(8, 32, 16), 256, 0, stream>>>(w1, w1t);
  tr_w2<<<dim3(32, 8, 16), 256, 0, stream>>>(w2, w2t);

  ln_fwd<<<16384, 256, 0, stream>>>(tgt, ln1_g, ln1_b, h);
  // QKV: M=16384, N=3072, K=1024 -> grid 12*64=768
  gemm256<0><<<768, 512, 0, stream>>>(h, wqkv_h, 3072, 1024, 12, bqkv, nullptr, nullptr, qkv, nullptr);
  attn_fwd<<<dim3(8, 512), 256, 0, stream>>>(qkv, ctx);
  // out-proj: N=1024, K=1024 -> grid 4*64=256
  gemm256<1><<<256, 512, 0, stream>>>(ctx, wout_h, 1024, 1024, 4, bout, tgt, nullptr, nullptr, out);

  ln_fwd<<<16384, 256, 0, stream>>>(out, ln3_g, ln3_b, h);
  gate_fwd<<<256, 256, 0, stream>>>(h, gate_w, task, out + 16777217, gd, mp);
  aux_fwd<<<1, 64, 0, stream>>>(mp, out + 16777216);
  bias2_add<<<16384, 256, 0, stream>>>(gd, b2, out);
  // MoE up: N=4096, K=1024 -> grid 16*64=1024
  gemm256<2><<<1024, 512, 0, stream>>>(h, w1t, 4096, 1024, 16, b1, nullptr, gd, uw, nullptr);
  // MoE down: N=1024, K=4096 -> grid 4*64=256
  gemm256<3><<<256, 512, 0, stream>>>(uw, w2t, 1024, 4096, 4, nullptr, out, nullptr, nullptr, out);
}

// Round 5
// 1068.607 us; speedup vs baseline: 1.2887x; 1.0854x over previous
//
#include <hip/hip_runtime.h>

typedef float f32x4 __attribute__((ext_vector_type(4)));
typedef _Float16 half_t;
typedef _Float16 h8 __attribute__((ext_vector_type(8)));
typedef _Float16 h4 __attribute__((ext_vector_type(4)));

__device__ __forceinline__ f32x4 mfma16(h8 a, h8 b, f32x4 c) {
  return __builtin_amdgcn_mfma_f32_16x16x32_f16(a, b, c, 0, 0, 0);
}

// ---------------- LayerNorm (f32 in -> f16 out) ----------------
__global__ __launch_bounds__(256) void ln_fwd(const float* __restrict__ x,
                                              const float* __restrict__ g,
                                              const float* __restrict__ b,
                                              half_t* __restrict__ out) {
  const int row = blockIdx.x;
  const int tid = threadIdx.x;
  const float4 v = ((const float4*)(x + (size_t)row * 1024))[tid];
  float s = v.x + v.y + v.z + v.w;
  float q = v.x * v.x + v.y * v.y + v.z * v.z + v.w * v.w;
#pragma unroll
  for (int m = 1; m < 64; m <<= 1) { s += __shfl_xor(s, m); q += __shfl_xor(q, m); }
  __shared__ float red[8];
  const int wave = tid >> 6, lane = tid & 63;
  if (lane == 0) { red[wave] = s; red[wave + 4] = q; }
  __syncthreads();
  s = red[0] + red[1] + red[2] + red[3];
  q = red[4] + red[5] + red[6] + red[7];
  const float mean = s * (1.0f / 1024.0f);
  const float var = q * (1.0f / 1024.0f) - mean * mean;
  const float rstd = rsqrtf(var + 1e-5f);
  const float4 gv = ((const float4*)g)[tid];
  const float4 bv = ((const float4*)b)[tid];
  h4 o;
  o[0] = (half_t)((v.x - mean) * rstd * gv.x + bv.x);
  o[1] = (half_t)((v.y - mean) * rstd * gv.y + bv.y);
  o[2] = (half_t)((v.z - mean) * rstd * gv.z + bv.z);
  o[3] = (half_t)((v.w - mean) * rstd * gv.w + bv.w);
  *(h4*)(out + (size_t)row * 1024 + tid * 4) = o;
}

// ---------------- f32 -> f16 convert ----------------
__global__ __launch_bounds__(256) void cvt_f2h(const float* __restrict__ in,
                                               half_t* __restrict__ out, int n) {
  const int i = (blockIdx.x * 256 + threadIdx.x) * 4;
  if (i < n) {
    const float4 v = *(const float4*)(in + i);
    h4 o = {(half_t)v.x, (half_t)v.y, (half_t)v.z, (half_t)v.w};
    *(h4*)(out + i) = o;
  }
}

// ---------------- w1 [E,D,H] -> w1t [(E*H), D]  (f16) ----------------
__global__ __launch_bounds__(256) void tr_w1(const float* __restrict__ w1,
                                             half_t* __restrict__ w1t) {
  __shared__ float tile[32][33];
  const int e = blockIdx.z;
  const int tx = threadIdx.x & 31, ty = threadIdx.x >> 5;
  const int hh = blockIdx.x * 32 + tx;
#pragma unroll
  for (int i = 0; i < 4; ++i) {
    const int d = blockIdx.y * 32 + ty + i * 8;
    tile[ty + i * 8][tx] = w1[(size_t)e * 262144 + (size_t)d * 256 + hh];
  }
  __syncthreads();
#pragma unroll
  for (int i = 0; i < 4; ++i) {
    const int hho = blockIdx.x * 32 + ty + i * 8;
    const int k = blockIdx.y * 32 + tx;
    w1t[(size_t)(e * 256 + hho) * 1024 + k] = (half_t)tile[tx][ty + i * 8];
  }
}

// ---------------- w2 [E,H,D] -> w2t [D, (E*H)]  (f16) ----------------
__global__ __launch_bounds__(256) void tr_w2(const float* __restrict__ w2,
                                             half_t* __restrict__ w2t) {
  __shared__ float tile[32][33];
  const int e = blockIdx.z;
  const int tx = threadIdx.x & 31, ty = threadIdx.x >> 5;
  const int d_in = blockIdx.x * 32 + tx;
#pragma unroll
  for (int i = 0; i < 4; ++i) {
    const int hh = blockIdx.y * 32 + ty + i * 8;
    tile[ty + i * 8][tx] = w2[(size_t)e * 262144 + (size_t)hh * 1024 + d_in];
  }
  __syncthreads();
#pragma unroll
  for (int i = 0; i < 4; ++i) {
    const int d = blockIdx.x * 32 + ty + i * 8;
    const int hh = blockIdx.y * 32 + tx;
    w2t[(size_t)d * 4096 + e * 256 + hh] = (half_t)tile[tx][ty + i * 8];
  }
}

// ---------------- V transpose: qkv V-part -> vt[bh][64 d][512 s] (f16) ----------------
__global__ __launch_bounds__(256) void tr_v(const half_t* __restrict__ qkv,
                                            half_t* __restrict__ vt) {
  __shared__ half_t tile[32][33];
  const int bh = blockIdx.z;
  const int b = bh >> 4, h = bh & 15;
  const int st = blockIdx.x, dt = blockIdx.y;
  const int tx = threadIdx.x & 31, ty = threadIdx.x >> 5;
#pragma unroll
  for (int i = 0; i < 4; ++i) {
    const int s = st * 32 + ty + i * 8;
    tile[ty + i * 8][tx] =
        qkv[(size_t)(b * 512 + s) * 3072 + 2048 + h * 64 + dt * 32 + tx];
  }
  __syncthreads();
#pragma unroll
  for (int i = 0; i < 4; ++i) {
    const int d = dt * 32 + ty + i * 8;
    vt[((size_t)bh * 64 + d) * 512 + st * 32 + tx] = tile[tx][ty + i * 8];
  }
}

// ---------------- 256x256 MFMA GEMM, A[M,K] x Bt[N,K]^T ----------------
template <int EPI>
__global__ __launch_bounds__(512, 2) void gemm256(const half_t* __restrict__ A,
                                                  const half_t* __restrict__ Bt,
                                                  int N, int K, int nbx,
                                                  const float* __restrict__ bias,
                                                  const float* __restrict__ res,
                                                  const float* __restrict__ gd,
                                                  half_t* __restrict__ Ch,
                                                  float* __restrict__ Cf) {
  __shared__ half_t lds[2][2][256 * 64];  // [slot][A/B][row*64 + col]
  const int tid = threadIdx.x;
  const int wave = tid >> 6, lane = tid & 63;
  const int l15 = lane & 15, g = lane >> 4;
  const int wr = wave >> 2, wc = wave & 3;

  const int nwg = gridDim.x;
  const int bid = blockIdx.x;
  const int swz = (bid & 7) * (nwg >> 3) + (bid >> 3);
  const int bx = swz % nbx, by = swz / nbx;

  const int NT = K >> 6;
  f32x4 acc[8][4] = {};

  auto stageAB = [&](int kt) {
    const int bt = kt & 1;
    const size_t abase = (size_t)(by * 256) * K + kt * 64;
    const size_t bbase = (size_t)(bx * 256) * K + kt * 64;
#pragma unroll
    for (int j = 0; j < 4; ++j) {
      const int c = tid + j * 512;
      const int row = c >> 3, sl = c & 7;
      const int col = (sl ^ (row & 7)) << 3;
      __builtin_amdgcn_global_load_lds(
          (const __attribute__((address_space(1))) void*)(A + abase + (size_t)row * K + col),
          (__attribute__((address_space(3))) void*)(&lds[bt][0][c * 8]), 16, 0, 0);
      __builtin_amdgcn_global_load_lds(
          (const __attribute__((address_space(1))) void*)(Bt + bbase + (size_t)row * K + col),
          (__attribute__((address_space(3))) void*)(&lds[bt][1][c * 8]), 16, 0, 0);
    }
  };

  stageAB(0);
  for (int kt = 0; kt < NT; ++kt) {
    const int bt = kt & 1;
    if (kt + 1 < NT) {
      stageAB(kt + 1);
      asm volatile("s_waitcnt vmcnt(8)" ::: "memory");
    } else {
      asm volatile("s_waitcnt vmcnt(0)" ::: "memory");
    }
    __builtin_amdgcn_s_barrier();

    h8 a0[4][2], a1[4][2], b0[2][2], b1[2][2];
#pragma unroll
    for (int m4 = 0; m4 < 4; ++m4)
#pragma unroll
      for (int kk = 0; kk < 2; ++kk) {
        const int row = wr * 128 + m4 * 16 + l15;
        const int sl = ((kk << 2) | g) ^ (row & 7);
        a0[m4][kk] = *(const h8*)(&lds[bt][0][row * 64 + sl * 8]);
      }
#pragma unroll
    for (int n2 = 0; n2 < 2; ++n2)
#pragma unroll
      for (int kk = 0; kk < 2; ++kk) {
        const int rowb0 = wc * 64 + n2 * 16 + l15;
        const int slb0 = ((kk << 2) | g) ^ (rowb0 & 7);
        b0[n2][kk] = *(const h8*)(&lds[bt][1][rowb0 * 64 + slb0 * 8]);
        const int rowb1 = wc * 64 + 32 + n2 * 16 + l15;
        const int slb1 = ((kk << 2) | g) ^ (rowb1 & 7);
        b1[n2][kk] = *(const h8*)(&lds[bt][1][rowb1 * 64 + slb1 * 8]);
      }
#pragma unroll
    for (int m4 = 0; m4 < 4; ++m4)
#pragma unroll
      for (int n2 = 0; n2 < 2; ++n2)
#pragma unroll
        for (int kk = 0; kk < 2; ++kk) {
          acc[m4][n2] = mfma16(a0[m4][kk], b0[n2][kk], acc[m4][n2]);
          acc[m4][2 + n2] = mfma16(a0[m4][kk], b1[n2][kk], acc[m4][2 + n2]);
        }
#pragma unroll
    for (int m4 = 0; m4 < 4; ++m4)
#pragma unroll
      for (int kk = 0; kk < 2; ++kk) {
        const int row = wr * 128 + 64 + m4 * 16 + l15;
        const int sl = ((kk << 2) | g) ^ (row & 7);
        a1[m4][kk] = *(const h8*)(&lds[bt][0][row * 64 + sl * 8]);
      }
#pragma unroll
    for (int m4 = 0; m4 < 4; ++m4)
#pragma unroll
      for (int n2 = 0; n2 < 2; ++n2)
#pragma unroll
        for (int kk = 0; kk < 2; ++kk) {
          acc[4 + m4][n2] = mfma16(a1[m4][kk], b0[n2][kk], acc[4 + m4][n2]);
          acc[4 + m4][2 + n2] = mfma16(a1[m4][kk], b1[n2][kk], acc[4 + m4][2 + n2]);
        }

    asm volatile("s_waitcnt lgkmcnt(0)" ::: "memory");
    __builtin_amdgcn_s_barrier();
  }

#pragma unroll
  for (int m = 0; m < 8; ++m) {
#pragma unroll
    for (int n = 0; n < 4; ++n) {
      const int col = bx * 256 + wc * 64 + n * 16 + l15;
      float bv = 0.0f;
      if constexpr (EPI != 3) bv = bias[col];
#pragma unroll
      for (int r = 0; r < 4; ++r) {
        const int row = by * 256 + wr * 128 + m * 16 + g * 4 + r;
        const float v = acc[m][n][r] + bv;
        if constexpr (EPI == 0) {
          Ch[(size_t)row * N + col] = (half_t)v;
        } else if constexpr (EPI == 1) {
          Cf[(size_t)row * N + col] = res[(size_t)row * N + col] + v;
        } else if constexpr (EPI == 2) {
          const float gel = 0.5f * v * (1.0f + erff(v * 0.70710678118f));
          Ch[(size_t)row * N + col] = (half_t)(gel * gd[row * 16 + (col >> 8)]);
        } else {
          Cf[(size_t)row * N + col] = res[(size_t)row * N + col] + v;
        }
      }
    }
  }
}

// ---------------- fused flash attention v2 ----------------
// grid 2048 flat (4 qtiles x 512 bh, XCD-swizzled); block 256 (4 waves x 32 q).
// 64-key K/V tiles double-buffered, XOR-swizzled (pre-swizzled global source),
// staged via global_load_lds; V pre-transposed globally (vt).
__global__ __launch_bounds__(256) void attn_fwd(const half_t* __restrict__ qkv,
                                                const half_t* __restrict__ vt,
                                                half_t* __restrict__ ctx) {
  __shared__ half_t K_s[2][64 * 64];
  __shared__ half_t V_s[2][64 * 64];
  __shared__ half_t P_s[4][32 * 72];
  const int tid = threadIdx.x;
  const int wave = tid >> 6, lane = tid & 63;
  const int l15 = lane & 15, g = lane >> 4;

  // XCD swizzle: head bh pinned to XCD (bh-chunks of 32 -> 4MB KV in one L2)
  const int fid = blockIdx.x;
  const int xcd = fid & 7, idx = fid >> 3;
  const int bh = xcd * 64 + (idx >> 7) * 32 + (idx & 31);
  const int qt = (idx >> 5) & 3;
  const int b = bh >> 4, h = bh & 15;

  // Q fragments (32 q rows per wave), 1/sqrt(dh)=0.125 folded
  h8 qreg[2][2];
#pragma unroll
  for (int m = 0; m < 2; ++m) {
    const size_t qrow = (size_t)(b * 512 + qt * 128 + wave * 32 + m * 16 + l15);
#pragma unroll
    for (int kk = 0; kk < 2; ++kk) {
      h8 t = *(const h8*)(qkv + qrow * 3072 + h * 64 + kk * 32 + g * 8);
      qreg[m][kk] = t * (half_t)0.125f;
    }
  }

  float mr[2][4], sr[2][4];
  f32x4 o[2][4] = {};
#pragma unroll
  for (int m = 0; m < 2; ++m)
#pragma unroll
    for (int r = 0; r < 4; ++r) { mr[m][r] = -1e30f; sr[m][r] = 0.0f; }

  const half_t* kg = qkv + (size_t)(b * 512) * 3072 + 1024 + h * 64;
  const half_t* vg = vt + (size_t)bh * 32768;

  auto stage = [&](int kt) {
    const int bt = kt & 1;
#pragma unroll
    for (int j = 0; j < 2; ++j) {
      const int s = tid + j * 256;
      const int row = s >> 3, sl = s & 7;
      const int col = (sl ^ (row & 7)) << 3;
      __builtin_amdgcn_global_load_lds(
          (const __attribute__((address_space(1))) void*)(kg + (size_t)(kt * 64 + row) * 3072 + col),
          (__attribute__((address_space(3))) void*)(&K_s[bt][s * 8]), 16, 0, 0);
      __builtin_amdgcn_global_load_lds(
          (const __attribute__((address_space(1))) void*)(vg + (size_t)row * 512 + kt * 64 + col),
          (__attribute__((address_space(3))) void*)(&V_s[bt][s * 8]), 16, 0, 0);
    }
  };

  stage(0);
  for (int kt = 0; kt < 8; ++kt) {
    const int bt = kt & 1;
    if (kt < 7) {
      stage(kt + 1);
      asm volatile("s_waitcnt vmcnt(4)" ::: "memory");
    } else {
      asm volatile("s_waitcnt vmcnt(0)" ::: "memory");
    }
    __builtin_amdgcn_s_barrier();

    // ---- QK^T: S[32q][64k] per wave ----
    f32x4 s_acc[2][4] = {};
    h8 bk[4][2];
#pragma unroll
    for (int n = 0; n < 4; ++n)
#pragma unroll
      for (int kk = 0; kk < 2; ++kk)
        bk[n][kk] = *(const h8*)(&K_s[bt][(n * 16 + l15) * 64 + (((kk * 4 + g) ^ (l15 & 7)) << 3)]);
#pragma unroll
    for (int m = 0; m < 2; ++m)
#pragma unroll
      for (int n = 0; n < 4; ++n)
#pragma unroll
        for (int kk = 0; kk < 2; ++kk)
          s_acc[m][n] = mfma16(qreg[m][kk], bk[n][kk], s_acc[m][n]);

    // ---- online softmax (row = m*16 + g*4 + r, keys n*16+l15) ----
#pragma unroll
    for (int m = 0; m < 2; ++m)
#pragma unroll
      for (int r = 0; r < 4; ++r) {
        float tm = fmaxf(fmaxf(s_acc[m][0][r], s_acc[m][1][r]),
                         fmaxf(s_acc[m][2][r], s_acc[m][3][r]));
#pragma unroll
        for (int msk = 1; msk < 16; msk <<= 1) tm = fmaxf(tm, __shfl_xor(tm, msk));
        const float mnew = fmaxf(mr[m][r], tm);
        const float al = __expf(mr[m][r] - mnew);
        mr[m][r] = mnew;
        float rs = 0.0f;
#pragma unroll
        for (int n = 0; n < 4; ++n) {
          const float p = __expf(s_acc[m][n][r] - mnew);
          rs += p;
          P_s[wave][(m * 16 + g * 4 + r) * 72 + n * 16 + l15] = (half_t)p;
        }
#pragma unroll
        for (int msk = 1; msk < 16; msk <<= 1) rs += __shfl_xor(rs, msk);
        sr[m][r] = sr[m][r] * al + rs;
#pragma unroll
        for (int d = 0; d < 4; ++d) o[m][d][r] *= al;
      }

    // ---- PV: O[32q][64d] += P[32q][64k] x V^T[64d][64k]^T ----
    h8 bv[4][2], pa[2][2];
#pragma unroll
    for (int n = 0; n < 4; ++n)
#pragma unroll
      for (int kk = 0; kk < 2; ++kk)
        bv[n][kk] = *(const h8*)(&V_s[bt][(n * 16 + l15) * 64 + (((kk * 4 + g) ^ (l15 & 7)) << 3)]);
#pragma unroll
    for (int m = 0; m < 2; ++m)
#pragma unroll
      for (int kk = 0; kk < 2; ++kk)
        pa[m][kk] = *(const h8*)(&P_s[wave][(m * 16 + l15) * 72 + kk * 32 + g * 8]);
#pragma unroll
    for (int m = 0; m < 2; ++m)
#pragma unroll
      for (int n = 0; n < 4; ++n)
#pragma unroll
        for (int kk = 0; kk < 2; ++kk)
          o[m][n] = mfma16(pa[m][kk], bv[n][kk], o[m][n]);

    asm volatile("s_waitcnt lgkmcnt(0)" ::: "memory");
    __builtin_amdgcn_s_barrier();
  }

#pragma unroll
  for (int m = 0; m < 2; ++m)
#pragma unroll
    for (int n = 0; n < 4; ++n)
#pragma unroll
      for (int r = 0; r < 4; ++r) {
        const size_t row = (size_t)(b * 512 + qt * 128 + wave * 32 + m * 16 + g * 4 + r);
        ctx[row * 1024 + h * 64 + n * 16 + l15] = (half_t)(o[m][n][r] / sr[m][r]);
      }
}

// ---------------- gating ----------------
__global__ __launch_bounds__(256) void gate_fwd(const half_t* __restrict__ h3,
                                                const float* __restrict__ gate_w,
                                                const int* __restrict__ task_id,
                                                float* __restrict__ probs,
                                                float* __restrict__ gd,
                                                float* __restrict__ mp) {
  const int tid = threadIdx.x, wave = tid >> 6, lane = tid & 63;
  const float* gw = gate_w + (size_t)task_id[0] * 16384;
  __shared__ float mp_part[16];
  if (tid < 16) mp_part[tid] = 0.0f;
  __syncthreads();
  float mpl[16];
#pragma unroll
  for (int e = 0; e < 16; ++e) mpl[e] = 0.0f;
  const int t0 = blockIdx.x * 64 + wave * 16;
  for (int tt = 0; tt < 16; ++tt) {
    const int t = t0 + tt;
    float acc[16];
#pragma unroll
    for (int e = 0; e < 16; ++e) acc[e] = 0.0f;
#pragma unroll
    for (int i = 0; i < 16; ++i) {
      const int d = i * 64 + lane;
      const float hv = (float)h3[(size_t)t * 1024 + d];
      const float4* gp = (const float4*)(gw + d * 16);
      const float4 g0 = gp[0], g1 = gp[1], g2 = gp[2], g3 = gp[3];
      acc[0] = fmaf(hv, g0.x, acc[0]);  acc[1] = fmaf(hv, g0.y, acc[1]);
      acc[2] = fmaf(hv, g0.z, acc[2]);  acc[3] = fmaf(hv, g0.w, acc[3]);
      acc[4] = fmaf(hv, g1.x, acc[4]);  acc[5] = fmaf(hv, g1.y, acc[5]);
      acc[6] = fmaf(hv, g1.z, acc[6]);  acc[7] = fmaf(hv, g1.w, acc[7]);
      acc[8] = fmaf(hv, g2.x, acc[8]);  acc[9] = fmaf(hv, g2.y, acc[9]);
      acc[10] = fmaf(hv, g2.z, acc[10]); acc[11] = fmaf(hv, g2.w, acc[11]);
      acc[12] = fmaf(hv, g3.x, acc[12]); acc[13] = fmaf(hv, g3.y, acc[13]);
      acc[14] = fmaf(hv, g3.z, acc[14]); acc[15] = fmaf(hv, g3.w, acc[15]);
    }
#pragma unroll
    for (int msk = 32; msk >= 1; msk >>= 1)
#pragma unroll
      for (int e = 0; e < 16; ++e) acc[e] += __shfl_xor(acc[e], msk);
    float mx = acc[0];
#pragma unroll
    for (int e = 1; e < 16; ++e) mx = fmaxf(mx, acc[e]);
    float p[16];
    float sum = 0.0f;
#pragma unroll
    for (int e = 0; e < 16; ++e) { p[e] = __expf(acc[e] - mx); sum += p[e]; }
    const float inv = 1.0f / sum;
#pragma unroll
    for (int e = 0; e < 16; ++e) p[e] *= inv;
    float myp = p[0];
#pragma unroll
    for (int e = 1; e < 16; ++e) myp = (lane == e) ? p[e] : myp;
    if (lane < 16) probs[(size_t)t * 16 + lane] = myp;
#pragma unroll
    for (int e = 0; e < 16; ++e) mpl[e] += p[e];
    float v[16];
#pragma unroll
    for (int e = 0; e < 16; ++e) v[e] = p[e];
    float topv[8];
    int topi[8];
#pragma unroll
    for (int k = 0; k < 8; ++k) {
      float vm = -1.0f;
      int im = 0;
#pragma unroll
      for (int e = 0; e < 16; ++e) {
        const bool gt = v[e] > vm;
        vm = gt ? v[e] : vm;
        im = gt ? e : im;
      }
      topv[k] = vm; topi[k] = im;
#pragma unroll
      for (int e = 0; e < 16; ++e) v[e] = (e == im) ? -1.0f : v[e];
    }
    float ts = 1e-6f;
#pragma unroll
    for (int k = 0; k < 8; ++k) ts += topv[k];
    const float tinv = 1.0f / ts;
    float gval = 0.0f;
#pragma unroll
    for (int k = 0; k < 8; ++k) gval = (topi[k] == lane) ? topv[k] * tinv : gval;
    if (lane < 16) gd[(size_t)t * 16 + lane] = gval;
  }
  if (lane == 0) {
#pragma unroll
    for (int e = 0; e < 16; ++e) atomicAdd(&mp_part[e], mpl[e]);
  }
  __syncthreads();
  if (tid < 16) atomicAdd(&mp[tid], mp_part[tid]);
}

// ---------------- aux loss ----------------
__global__ void aux_fwd(const float* __restrict__ mp, float* __restrict__ out) {
  if (threadIdx.x == 0) {
    float a = 0.0f;
    for (int e = 0; e < 16; ++e) {
      const float m = mp[e] * (1.0f / 16384.0f);
      a += m * logf(m + 1e-6f);
    }
    out[0] = 5e-4f * a;
  }
}

// ---------------- d_out += gate_dense @ b2 (16 tokens/block) ----------------
__global__ __launch_bounds__(256) void bias2_add(const float* __restrict__ gd,
                                                 const float* __restrict__ b2,
                                                 float* __restrict__ out) {
  const int t0 = blockIdx.x * 16;
  const int tid = threadIdx.x;
  __shared__ float gds[16][16];
  gds[tid >> 4][tid & 15] = gd[(size_t)(t0 + (tid >> 4)) * 16 + (tid & 15)];
  __syncthreads();
  float4 bv[16];
#pragma unroll
  for (int e = 0; e < 16; ++e) bv[e] = *(const float4*)(b2 + e * 1024 + tid * 4);
  for (int tt = 0; tt < 16; ++tt) {
    float4 v = *(const float4*)(out + (size_t)(t0 + tt) * 1024 + tid * 4);
#pragma unroll
    for (int e = 0; e < 16; ++e) {
      const float gv = gds[tt][e];
      v.x = fmaf(gv, bv[e].x, v.x);
      v.y = fmaf(gv, bv[e].y, v.y);
      v.z = fmaf(gv, bv[e].z, v.z);
      v.w = fmaf(gv, bv[e].w, v.w);
    }
    *(float4*)(out + (size_t)(t0 + tt) * 1024 + tid * 4) = v;
  }
}

extern "C" void kernel_launch(void* const* d_in, const int* in_sizes, int n_in,
                              void* d_out, int out_size, void* d_ws, size_t ws_size,
                              hipStream_t stream) {
  const float* tgt = (const float*)d_in[0];
  const float* ln1_g = (const float*)d_in[2];
  const float* ln1_b = (const float*)d_in[3];
  const float* ln3_g = (const float*)d_in[4];
  const float* ln3_b = (const float*)d_in[5];
  const float* Wqkv = (const float*)d_in[6];
  const float* bqkv = (const float*)d_in[7];
  const float* Wout = (const float*)d_in[8];
  const float* bout = (const float*)d_in[9];
  const float* gate_w = (const float*)d_in[10];
  const float* w1 = (const float*)d_in[11];
  const float* b1 = (const float*)d_in[12];
  const float* w2 = (const float*)d_in[13];
  const float* b2 = (const float*)d_in[14];
  const int* task = (const int*)d_in[15];
  float* out = (float*)d_out;
  char* ws = (char*)d_ws;

  // ws layout (bytes):
  half_t* h = (half_t*)(ws + 0ull);                   // 32MB [T,1024]; also vt overlay
  half_t* vt = (half_t*)(ws + 0ull);                  // 32MB [512 bh][64 d][512 s] (h dead during attn)
  half_t* qkv = (half_t*)(ws + 33554432ull);          // 96MB  [T,3072]
  half_t* ctx = (half_t*)(ws + 134217728ull);         // 32MB  [T,1024]
  half_t* uw = (half_t*)(ws + 33554432ull);           // 128MB [T,4096] overlays qkv+ctx
  half_t* wqkv_h = (half_t*)(ws + 167772160ull);      // 6MB
  half_t* wout_h = (half_t*)(ws + 174063616ull);      // 2MB
  half_t* w1t = (half_t*)(ws + 176160768ull);         // 8MB
  half_t* w2t = (half_t*)(ws + 184549376ull);         // 8MB
  float* gd = (float*)(ws + 192937984ull);            // 1MB [T,16]
  float* mp = (float*)(ws + 193986560ull);            // 64B [16]

  hipMemsetAsync(mp, 0, 64, stream);
  cvt_f2h<<<3072, 256, 0, stream>>>(Wqkv, wqkv_h, 3145728);
  cvt_f2h<<<1024, 256, 0, stream>>>(Wout, wout_h, 1048576);
  tr_w1<<<dim3(8, 32, 16), 256, 0, stream>>>(w1, w1t);
  tr_w2<<<dim3(32, 8, 16), 256, 0, stream>>>(w2, w2t);

  ln_fwd<<<16384, 256, 0, stream>>>(tgt, ln1_g, ln1_b, h);
  gemm256<0><<<768, 512, 0, stream>>>(h, wqkv_h, 3072, 1024, 12, bqkv, nullptr, nullptr, qkv, nullptr);
  tr_v<<<dim3(16, 2, 512), 256, 0, stream>>>(qkv, vt);
  attn_fwd<<<2048, 256, 0, stream>>>(qkv, vt, ctx);
  gemm256<1><<<256, 512, 0, stream>>>(ctx, wout_h, 1024, 1024, 4, bout, tgt, nullptr, nullptr, out);

  ln_fwd<<<16384, 256, 0, stream>>>(out, ln3_g, ln3_b, h);
  gate_fwd<<<256, 256, 0, stream>>>(h, gate_w, task, out + 16777217, gd, mp);
  aux_fwd<<<1, 64, 0, stream>>>(mp, out + 16777216);
  bias2_add<<<1024, 256, 0, stream>>>(gd, b2, out);
  gemm256<2><<<1024, 512, 0, stream>>>(h, w1t, 4096, 1024, 16, b1, nullptr, gd, uw, nullptr);
  gemm256<3><<<256, 512, 0, stream>>>(uw, w2t, 1024, 4096, 4, nullptr, out, nullptr, nullptr, out);
}